// Round 15
// baseline (475.663 us; speedup 1.0000x reference)
//
#include <hip/hip_runtime.h>
#include <hip/hip_bf16.h>

#define N_NODES 50000
#define N_EDGES 400000
#define NB 64
#define SCB 196   // ceil(N_NODES/256)
#define CGB 1024
#define XFB 25000 // N_NODES*128/256 exactly

typedef unsigned short u16;
typedef unsigned int u32;
typedef __attribute__((ext_vector_type(8))) short s16x8;
typedef __attribute__((ext_vector_type(4))) float f32x4;

__device__ __forceinline__ u16 f2b(float f) {
  __hip_bfloat16 h = __float2bfloat16(f);
  return *reinterpret_cast<const u16*>(&h);
}
__device__ __forceinline__ float b2f(u16 u) {
  u32 v = ((u32)u) << 16;
  return *reinterpret_cast<const float*>(&v);
}
__device__ __forceinline__ s16x8 scl8(s16x8 v, float dg) {
  s16x8 r;
#pragma unroll
  for (int i = 0; i < 8; ++i) {
    float f = b2f((u16)v[i]) * dg;
    r[i] = (short)f2b(f);
  }
  return r;
}

// ---------------- merged: x f32->bf16 (blocks < XFB) + deg histogram ----------------
__global__ void k_prep(const float* __restrict__ x, u16* __restrict__ xb,
                       const int* __restrict__ colv, int* __restrict__ deg) {
  if (blockIdx.x < XFB) {
    int i = blockIdx.x * 256 + threadIdx.x;
    xb[i] = f2b(x[i]);
  } else {
    int e = (blockIdx.x - XFB) * 256 + threadIdx.x;
    if (e < N_EDGES) atomicAdd(&deg[colv[e]], 1);
  }
}

// ---------------- batched small f32 matmuls ----------------
struct MMOp { const float* A; const float* B; const float* add; float* C;
              int lda, r0, ldb, K2, N, rows; };
struct MMBatch { MMOp op[13]; };

__global__ void k_mmb(MMBatch mb) {
  MMOp o = mb.op[blockIdx.y];
  int i = blockIdx.x;
  int n = threadIdx.x;
  if (i >= o.rows || n >= o.N) return;
  float acc = o.add ? o.add[(size_t)i * o.N + n] : 0.f;
  for (int k = 0; k < o.K2; ++k)
    acc = fmaf(o.A[(size_t)(o.r0 + i) * o.lda + k], o.B[(size_t)k * o.ldb + n], acc);
  o.C[(size_t)i * o.N + n] = acc;
}

// ---------------- pack composed weights (bf16, N-major) + bias pack (extra block) ----------------
__global__ void k_pack_iter(const float* __restrict__ N2a, const float* __restrict__ WadjX,
                            const float* __restrict__ A1, const float* __restrict__ WaggE,
                            const float* __restrict__ C1, const float* __restrict__ Wdegx,
                            const float* __restrict__ B1,
                            const float* __restrict__ d2, const float* __restrict__ ddeg,
                            const float* __restrict__ c0,
                            float* __restrict__ bc, float* __restrict__ bd,
                            u16* __restrict__ Wt) {
  if (blockIdx.x == 336) {   // bias-pack block
    int t = threadIdx.x;
    if (t < 192) {
      bc[t] = (t < 128) ? d2[t] : 0.f;
      bd[t] = (t < 128) ? ddeg[t] : c0[t - 128];
    }
    return;
  }
  int i = blockIdx.x * 256 + threadIdx.x;
  if (i >= 192 * 448) return;
  int n = i / 448, k = i % 448;
  float v;
  if (k < 128)      v = (n < 128) ? N2a[(size_t)k * 128 + n] : 0.f;
  else if (k < 256) { int kk = k - 128; v = (n < 128) ? WadjX[(size_t)kk * 128 + n] : A1[(size_t)kk * 64 + (n - 128)]; }
  else if (k < 320) { int kk = k - 256; v = (n < 128) ? WaggE[(size_t)kk * 128 + n] : C1[(size_t)kk * 64 + (n - 128)]; }
  else              { int kk = k - 320; v = (n < 128) ? Wdegx[(size_t)kk * 128 + n] : B1[(size_t)kk * 64 + (n - 128)]; }
  Wt[(size_t)n * 448 + k] = f2b(v);
}

// ---------------- 3-phase parallel exclusive scan over deg ----------------
__global__ void k_scan1(const int* __restrict__ deg, int* __restrict__ bsum, int n) {
  __shared__ int red[256];
  int t = threadIdx.x;
  int i = blockIdx.x * 256 + t;
  red[t] = (i < n) ? deg[i] : 0;
  __syncthreads();
  for (int s = 128; s > 0; s >>= 1) {
    if (t < s) red[t] += red[t + s];
    __syncthreads();
  }
  if (t == 0) bsum[blockIdx.x] = red[0];
}

__global__ void k_scan2(int* __restrict__ bsum, int nb) {
  __shared__ int sh[256];
  int t = threadIdx.x;
  sh[t] = (t < nb) ? bsum[t] : 0;
  __syncthreads();
  for (int d = 1; d < 256; d <<= 1) {
    int v = (t >= d) ? sh[t - d] : 0;
    __syncthreads();
    sh[t] += v;
    __syncthreads();
  }
  if (t < nb) bsum[t] = sh[t];   // inclusive block prefix
}

__global__ void k_scan3(const int* __restrict__ deg, const int* __restrict__ bsum,
                        int* __restrict__ rowptr, int* __restrict__ cursor,
                        float* __restrict__ degf, int n) {
  __shared__ int sh[256];
  int t = threadIdx.x;
  int i = blockIdx.x * 256 + t;
  int d = (i < n) ? deg[i] : 0;
  sh[t] = d;
  __syncthreads();
  for (int s = 1; s < 256; s <<= 1) {
    int v = (t >= s) ? sh[t - s] : 0;
    __syncthreads();
    sh[t] += v;
    __syncthreads();
  }
  int base = (blockIdx.x > 0) ? bsum[blockIdx.x - 1] : 0;
  int ex = base + sh[t] - d;
  if (i < n) {
    rowptr[i] = ex;
    cursor[i] = ex;
    degf[i] = (float)d;
    if (i == n - 1) rowptr[n] = ex + d;
  }
}

// ---------------- CSR fill (wave per edge): crow + cnt + eattr permute->bf16 ----------------
// eattr reads are sequential (edge order); eaperm ends up CSR-ordered so k_agg
// streams it. Replaces the random 102 MB f32 eattr gather (r5: FETCH=97.8MB).
__global__ void k_fill(const int* __restrict__ rowv, const int* __restrict__ colv,
                       const int* __restrict__ batch, const float* __restrict__ eattr,
                       int* __restrict__ cursor, int* __restrict__ crow,
                       u16* __restrict__ eaperm, float* __restrict__ cnt) {
  int e = blockIdx.x * 4 + (threadIdx.x >> 6);
  if (e >= N_EDGES) return;
  int l = threadIdx.x & 63;
  int c = colv[e];
  int pos;
  if (l == 0) {
    int r = rowv[e];
    pos = atomicAdd(&cursor[c], 1);
    crow[pos] = r;
    atomicAdd(&cnt[(size_t)r * 64 + batch[c]], 1.0f);
  }
  pos = __shfl(pos, 0);
  eaperm[(size_t)pos * 64 + l] = f2b(eattr[(size_t)e * 64 + l]);
}

// ---------------- merged: cnt-GEMM partials (blocks < CGB) + sorted-batch pooling ----------------
__global__ __launch_bounds__(256)
void k_cntpool(const float* __restrict__ cnt, const u16* __restrict__ xb,
               float* __restrict__ Ppart,
               const u16* __restrict__ aggE, const float* __restrict__ degf,
               const int* __restrict__ batch,
               float* __restrict__ npool, float* __restrict__ PaggE,
               float* __restrict__ pdeg, int n) {
  __shared__ float cs[8][64];
  int t = threadIdx.x;
  if (blockIdx.x < CGB) {
    int c = t & 127, half = t >> 7;
    float acc[32];
#pragma unroll
    for (int q = 0; q < 32; ++q) acc[q] = 0.f;
    int span = (N_NODES + CGB - 1) / CGB;
    int v0 = blockIdx.x * span;
    int v1 = v0 + span; if (v1 > N_NODES) v1 = N_NODES;
    for (int vt = v0; vt < v1; vt += 8) {
      int nv = v1 - vt; if (nv > 8) nv = 8;
      for (int idx = t; idx < nv * 64; idx += 256)
        cs[idx >> 6][idx & 63] = cnt[(size_t)(vt + (idx >> 6)) * 64 + (idx & 63)];
      __syncthreads();
      for (int j = 0; j < nv; ++j) {
        float xv = b2f(xb[(size_t)(vt + j) * 128 + c]);
#pragma unroll
        for (int q = 0; q < 32; ++q) acc[q] = fmaf(cs[j][half * 32 + q], xv, acc[q]);
      }
      __syncthreads();
    }
#pragma unroll
    for (int q = 0; q < 32; ++q)
      Ppart[(size_t)blockIdx.x * 8192 + (size_t)(half * 32 + q) * 128 + c] = acc[q];
  } else {
    int n0 = (blockIdx.x - CGB) * 128;
    if (n0 >= n) return;
    int n1 = n0 + 128; if (n1 > n) n1 = n;
    float acc = 0.f;
    int cur = batch[n0];
    for (int i = n0; i < n1; ++i) {
      int bi = batch[i];
      if (bi != cur) {
        if (t < 128) atomicAdd(&npool[cur * 128 + t], acc);
        else if (t < 192) atomicAdd(&PaggE[cur * 64 + (t - 128)], acc);
        else if (t == 192) atomicAdd(&pdeg[cur], acc);
        acc = 0.f; cur = bi;
      }
      if (t < 128) acc += b2f(xb[(size_t)i * 128 + t]);
      else if (t < 192) acc += b2f(aggE[(size_t)i * 64 + (t - 128)]);
      else if (t == 192) acc += degf[i];
    }
    if (t < 128) atomicAdd(&npool[cur * 128 + t], acc);
    else if (t < 192) atomicAdd(&PaggE[cur * 64 + (t - 128)], acc);
    else if (t == 192) atomicAdd(&pdeg[cur], acc);
  }
}

// ---------------- CSR gather segment-sums (8/4/1 unrolled; eaperm streamed) ----------------
template<bool DOE>
__global__ void k_agg(const u16* __restrict__ xb, const u16* __restrict__ eaperm,
                      const int* __restrict__ rowptr, const int* __restrict__ crow,
                      u16* __restrict__ outX, u16* __restrict__ outE) {
  int wpb = blockDim.x >> 6;
  int w = blockIdx.x * wpb + (threadIdx.x >> 6);
  int l = threadIdx.x & 63;
  int nw = gridDim.x * wpb;
  for (int v = w; v < N_NODES; v += nw) {
    int s = rowptr[v], e1 = rowptr[v + 1];
    float ax0 = 0.f, ax1 = 0.f, ae = 0.f;
    int i = s;
    for (; i + 7 < e1; i += 8) {
      u32 a[8]; float ev[8];
#pragma unroll
      for (int j = 0; j < 8; ++j)
        a[j] = *reinterpret_cast<const u32*>(&xb[(size_t)crow[i + j] * 128 + l * 2]);
      if (DOE) {
#pragma unroll
        for (int j = 0; j < 8; ++j)
          ev[j] = b2f(eaperm[(size_t)(i + j) * 64 + l]);
      }
#pragma unroll
      for (int j = 0; j < 8; ++j) {
        ax0 += b2f((u16)(a[j] & 0xffff));
        ax1 += b2f((u16)(a[j] >> 16));
        if (DOE) ae += ev[j];
      }
    }
    for (; i + 3 < e1; i += 4) {
      u32 a[4]; float ev[4];
#pragma unroll
      for (int j = 0; j < 4; ++j)
        a[j] = *reinterpret_cast<const u32*>(&xb[(size_t)crow[i + j] * 128 + l * 2]);
      if (DOE) {
#pragma unroll
        for (int j = 0; j < 4; ++j)
          ev[j] = b2f(eaperm[(size_t)(i + j) * 64 + l]);
      }
#pragma unroll
      for (int j = 0; j < 4; ++j) {
        ax0 += b2f((u16)(a[j] & 0xffff));
        ax1 += b2f((u16)(a[j] >> 16));
        if (DOE) ae += ev[j];
      }
    }
    for (; i < e1; ++i) {
      u32 a = *reinterpret_cast<const u32*>(&xb[(size_t)crow[i] * 128 + l * 2]);
      ax0 += b2f((u16)(a & 0xffff));
      ax1 += b2f((u16)(a >> 16));
      if (DOE) ae += b2f(eaperm[(size_t)i * 64 + l]);
    }
    u32 pk = ((u32)f2b(ax1) << 16) | (u32)f2b(ax0);
    *reinterpret_cast<u32*>(&outX[(size_t)v * 128 + l * 2]) = pk;
    if (DOE) outE[(size_t)v * 64 + l] = f2b(ae);
  }
}

// ---------------- node GEMM v3: A direct-from-global, B LDS-staged post-barrier ----------------
struct Chunks { const u16* src[7]; int width[7]; int koff[7]; int scl[7]; };

__global__ __launch_bounds__(256)
void gemm_fused3(const u16* __restrict__ Wt,
                 const float* __restrict__ bc, const float* __restrict__ bd,
                 const float* __restrict__ degf, Chunks ch, int M,
                 u16* __restrict__ outb0, u16* __restrict__ outb1)
{
  constexpr int LDA = 72;
  __shared__ u16 Bs[192 * LDA];    // 27648 B; Cs (64*200*2 = 25600 B) aliases it
  const int t = threadIdx.x;
  const int wv = t >> 6, lane = t & 63, lr = lane & 15, lg = lane >> 4;
  const int bm0 = blockIdx.x * 64;
  const int wb = wv * 16;

  f32x4 acc[12];
#pragma unroll
  for (int f = 0; f < 12; ++f) acc[f] = (f32x4){0.f, 0.f, 0.f, 0.f};

  int arow = bm0 + wb + lr;
  if (arow >= M) arow = M - 1;
  const float dg = degf[arow];

  const int br0 = t >> 2;
  const int bo  = (t & 3) * 16;

#pragma unroll
  for (int c = 0; c < 7; ++c) {
    const u16* ap = ch.src[c] + (size_t)arow * ch.width[c] + ch.koff[c];
    s16x8 af0 = *reinterpret_cast<const s16x8*>(ap + lg * 8);
    s16x8 af1 = *reinterpret_cast<const s16x8*>(ap + 32 + lg * 8);
    if (ch.scl[c]) { af0 = scl8(af0, dg); af1 = scl8(af1, dg); }

    __syncthreads();
#pragma unroll
    for (int p = 0; p < 3; ++p) {
      const u16* bp = Wt + (size_t)(p * 64 + br0) * 448 + c * 64 + bo;
      uint4 b0 = *reinterpret_cast<const uint4*>(bp);
      uint4 b1 = *reinterpret_cast<const uint4*>(bp + 8);
      *reinterpret_cast<uint4*>(&Bs[(p * 64 + br0) * LDA + bo])     = b0;
      *reinterpret_cast<uint4*>(&Bs[(p * 64 + br0) * LDA + bo + 8]) = b1;
    }
    __syncthreads();

#pragma unroll
    for (int f = 0; f < 12; ++f) {
      s16x8 bf = *reinterpret_cast<const s16x8*>(&Bs[(f * 16 + lr) * LDA + lg * 8]);
      acc[f] = __builtin_amdgcn_mfma_f32_16x16x32_bf16(af0, bf, acc[f], 0, 0, 0);
    }
#pragma unroll
    for (int f = 0; f < 12; ++f) {
      s16x8 bf = *reinterpret_cast<const s16x8*>(&Bs[(f * 16 + lr) * LDA + 32 + lg * 8]);
      acc[f] = __builtin_amdgcn_mfma_f32_16x16x32_bf16(af1, bf, acc[f], 0, 0, 0);
    }
  }

  __syncthreads();
  u16 (*Cs)[200] = reinterpret_cast<u16(*)[200]>(Bs);
#pragma unroll
  for (int rr = 0; rr < 4; ++rr) {
    int lrow = wb + lg * 4 + rr;
    int grow = bm0 + lrow;
    float dgr = degf[(grow < M) ? grow : (M - 1)];
#pragma unroll
    for (int f = 0; f < 12; ++f) {
      int col = f * 16 + lr;
      float v = acc[f][rr] + bc[col] + dgr * bd[col];
      Cs[lrow][col] = f2b(v);
    }
  }
  __syncthreads();

#pragma unroll
  for (int p = 0; p < 4; ++p) {
    int r = p * 16 + (t >> 4), c = (t & 15) * 8;
    if (bm0 + r < M)
      *reinterpret_cast<uint4*>(&outb0[(size_t)(bm0 + r) * 128 + c]) =
          *reinterpret_cast<const uint4*>(&Cs[r][c]);
  }
#pragma unroll
  for (int p = 0; p < 2; ++p) {
    int r = p * 32 + (t >> 3), c = (t & 7) * 8;
    if (bm0 + r < M)
      *reinterpret_cast<uint4*>(&outb1[(size_t)(bm0 + r) * 64 + c]) =
          *reinterpret_cast<const uint4*>(&Cs[r][128 + c]);
  }
}

// ---------------- head: Ppart-reduce + msg_pool + global MLP + final MLP ----------------
__global__ void k_head(const float* __restrict__ npool, const float* __restrict__ Ppart,
                       const float* __restrict__ PaggE, const float* __restrict__ pdeg,
                       const float* __restrict__ G1a, const float* __restrict__ G1b,
                       const float* __restrict__ e1,
                       const float* __restrict__ g2W0, const float* __restrict__ g2b0,
                       const float* __restrict__ g2W1, const float* __restrict__ g2b1,
                       const float* __restrict__ fW0, const float* __restrict__ fb0,
                       const float* __restrict__ fW1, const float* __restrict__ fb1,
                       float* __restrict__ out) {
  __shared__ float padj[128], r0[256], r1[128], r2[128], r3[256], red[256];
  int b = blockIdx.x, t = threadIdx.x;
  if (t < 128) {
    float s = 0.f;
    for (int j = 0; j < CGB; ++j) s += Ppart[(size_t)j * 8192 + (size_t)b * 128 + t];
    padj[t] = s;
  }
  __syncthreads();
  if (t < 128) {
    float a = pdeg[b] * e1[t];
    for (int k = 0; k < 128; ++k) a = fmaf(padj[k], G1a[(size_t)k * 128 + t], a);
    for (int k = 0; k < 64;  ++k) a = fmaf(PaggE[(size_t)b * 64 + k],  G1b[(size_t)k * 128 + t], a);
    r0[128 + t] = a;
    r0[t] = npool[(size_t)b * 128 + t];
  }
  __syncthreads();
  if (t < 128) {
    float a = g2b0[t];
    for (int k = 0; k < 256; ++k) a = fmaf(r0[k], g2W0[(size_t)k * 128 + t], a);
    r1[t] = a;
  }
  __syncthreads();
  if (t < 128) {
    float a = g2b1[t];
    for (int k = 0; k < 128; ++k) a = fmaf(r1[k], g2W1[(size_t)k * 128 + t], a);
    r2[t] = a;
  }
  __syncthreads();
  {
    float a = fb0[t];
    for (int k = 0; k < 128; ++k) a = fmaf(r2[k], fW0[(size_t)k * 256 + t], a);
    r3[t] = a;
  }
  __syncthreads();
  red[t] = r3[t] * fW1[t];
  __syncthreads();
  for (int s = 128; s > 0; s >>= 1) {
    if (t < s) red[t] += red[t + s];
    __syncthreads();
  }
  if (t == 0) out[b] = red[0] + fb1[0];
}

extern "C" void kernel_launch(void* const* d_in, const int* in_sizes, int n_in,
                              void* d_out, int out_size, void* d_ws, size_t ws_size,
                              hipStream_t stream) {
  const float* x     = (const float*)d_in[0];
  const int*   eidx  = (const int*)d_in[1];
  const float* eattr = (const float*)d_in[2];
  const int*   batch = (const int*)d_in[3];
  const float* eW0 = (const float*)d_in[4];  const float* eb0 = (const float*)d_in[5];
  const float* eW1 = (const float*)d_in[6];  const float* eb1 = (const float*)d_in[7];
  const float* n1W0 = (const float*)d_in[8]; const float* n1b0 = (const float*)d_in[9];
  const float* n1W1 = (const float*)d_in[10];const float* n1b1 = (const float*)d_in[11];
  const float* n2W0 = (const float*)d_in[12];const float* n2b0 = (const float*)d_in[13];
  const float* n2W1 = (const float*)d_in[14];const float* n2b1 = (const float*)d_in[15];
  const float* g1W0 = (const float*)d_in[16];const float* g1b0 = (const float*)d_in[17];
  const float* g1W1 = (const float*)d_in[18];const float* g1b1 = (const float*)d_in[19];
  const float* g2W0 = (const float*)d_in[20];const float* g2b0 = (const float*)d_in[21];
  const float* g2W1 = (const float*)d_in[22];const float* g2b1 = (const float*)d_in[23];
  const float* fW0 = (const float*)d_in[24]; const float* fb0 = (const float*)d_in[25];
  const float* fW1 = (const float*)d_in[26]; const float* fb1 = (const float*)d_in[27];

  const int* rowv = eidx;
  const int* colv = eidx + N_EDGES;

  char* ws = (char*)d_ws;
  size_t off = 0;
  auto alloc = [&](size_t bytes) -> void* {
    void* p = ws + off; off = (off + bytes + 255) & ~(size_t)255; return p;
  };
  u16*   x_b    = (u16*)alloc((size_t)N_NODES * 128 * 2);
  u16*   adjX_b = (u16*)alloc((size_t)N_NODES * 128 * 2);
  u16*   aggE_b = (u16*)alloc((size_t)N_NODES * 64 * 2);
  u16*   eaperm = (u16*)alloc((size_t)N_EDGES * 64 * 2);
  float* degf   = (float*)alloc((size_t)N_NODES * 4);
  int*   rowptr = (int*)alloc((size_t)(N_NODES + 1) * 4);
  int*   crow   = (int*)alloc((size_t)N_EDGES * 4);
  int*   bsum   = (int*)alloc((size_t)256 * 4);
  float* Ppart  = (float*)alloc((size_t)CGB * 8192 * 4);
  // ---- zeroed region (single memset) ----
  char*  zstart = ws + off;
  int*   cursor = (int*)alloc((size_t)N_NODES * 4);
  float* cnt    = (float*)alloc((size_t)N_NODES * 64 * 4);
  float* npool  = (float*)alloc((size_t)NB * 128 * 4);
  float* PaggE  = (float*)alloc((size_t)NB * 64 * 4);
  float* pdeg   = (float*)alloc((size_t)NB * 4);
  size_t zbytes = (size_t)((ws + off) - zstart);
  // ---- f32 weight-composition scratch ----
  float* N1a   = (float*)alloc(128 * 128 * 4);
  float* N1b   = (float*)alloc(64 * 128 * 4);
  float* N2a   = (float*)alloc(128 * 128 * 4);
  float* N2b   = (float*)alloc(128 * 128 * 4);
  float* A1    = (float*)alloc(128 * 64 * 4);
  float* B1    = (float*)alloc(128 * 64 * 4);
  float* C1    = (float*)alloc(64 * 64 * 4);
  float* G1a   = (float*)alloc(128 * 128 * 4);
  float* G1b   = (float*)alloc(64 * 128 * 4);
  float* T1    = (float*)alloc(64 * 128 * 4);
  float* U1    = (float*)alloc(128 * 128 * 4);
  float* WadjX = (float*)alloc(128 * 128 * 4);
  float* WaggE = (float*)alloc(64 * 128 * 4);
  float* Wdegx = (float*)alloc(128 * 128 * 4);
  float* c0    = (float*)alloc(64 * 4);
  float* d1    = (float*)alloc(128 * 4);
  float* d2    = (float*)alloc(128 * 4);
  float* q2    = (float*)alloc(128 * 4);
  float* ddeg  = (float*)alloc(128 * 4);
  float* e1    = (float*)alloc(128 * 4);
  float* bc    = (float*)alloc(192 * 4);
  float* bd    = (float*)alloc(192 * 4);
  u16*   BigWt = (u16*)alloc((size_t)192 * 448 * 2);
  (void)ws_size; (void)in_sizes; (void)n_in; (void)out_size;

  // ---- one memset for everything needing zeros ----
  hipMemsetAsync(zstart, 0, zbytes, stream);

  // x -> bf16 + deg histogram (merged)
  k_prep<<<XFB + (N_EDGES + 255) / 256, 256, 0, stream>>>(x, x_b, colv, cursor);

  // ---- weight composition, level-batched (3 levels) ----
  {
    MMBatch L1{};
    L1.op[0]  = {n1W0, n1W1, nullptr, N1a, 128, 0,   128, 128, 128, 128};
    L1.op[1]  = {n1W0, n1W1, nullptr, N1b, 128, 128, 128, 128, 128, 64};
    L1.op[2]  = {n2W0, n2W1, nullptr, N2a, 128, 0,   128, 128, 128, 128};
    L1.op[3]  = {n2W0, n2W1, nullptr, N2b, 128, 128, 128, 128, 128, 128};
    L1.op[4]  = {eW0,  eW1,  nullptr, A1,  128, 0,   64,  128, 64,  128};
    L1.op[5]  = {eW0,  eW1,  nullptr, B1,  128, 128, 64,  128, 64,  128};
    L1.op[6]  = {eW0,  eW1,  nullptr, C1,  128, 256, 64,  128, 64,  64};
    L1.op[7]  = {g1W0, g1W1, nullptr, G1a, 128, 0,   128, 128, 128, 128};
    L1.op[8]  = {g1W0, g1W1, nullptr, G1b, 128, 128, 128, 128, 128, 64};
    L1.op[9]  = {eb0,  eW1,  eb1,     c0,  128, 0,   64,  128, 64,  1};
    L1.op[10] = {n1b0, n1W1, n1b1,    d1,  128, 0,   128, 128, 128, 1};
    L1.op[11] = {n2b0, n2W1, n2b1,    d2,  128, 0,   128, 128, 128, 1};
    L1.op[12] = {g1b0, g1W1, g1b1,    e1,  128, 0,   128, 128, 128, 1};
    k_mmb<<<dim3(128, 13), 128, 0, stream>>>(L1);

    MMBatch L2{};
    L2.op[0] = {N1b, N2b, nullptr, T1, 128, 0, 128, 128, 128, 64};
    L2.op[1] = {N1a, N2b, nullptr, U1, 128, 0, 128, 128, 128, 128};
    L2.op[2] = {c0,  N1b, d1,      q2, 64,  0, 128, 64,  128, 1};   // q2 = c0@N1b + d1
    for (int j = 3; j < 13; ++j) L2.op[j] = {nullptr, nullptr, nullptr, nullptr, 0, 0, 0, 0, 0, 0};
    k_mmb<<<dim3(128, 3), 128, 0, stream>>>(L2);

    MMBatch L3{};
    L3.op[0] = {A1, T1, U1,      WadjX, 64,  0, 128, 64,  128, 128};
    L3.op[1] = {C1, T1, nullptr, WaggE, 64,  0, 128, 64,  128, 64};
    L3.op[2] = {B1, T1, nullptr, Wdegx, 64,  0, 128, 64,  128, 128};
    L3.op[3] = {q2, N2b, nullptr, ddeg, 128, 0, 128, 128, 128, 1};  // ddeg = q2@N2b
    for (int j = 4; j < 13; ++j) L3.op[j] = {nullptr, nullptr, nullptr, nullptr, 0, 0, 0, 0, 0, 0};
    k_mmb<<<dim3(128, 4), 128, 0, stream>>>(L3);
  }
  k_pack_iter<<<337, 256, 0, stream>>>(N2a, WadjX, A1, WaggE, C1, Wdegx, B1,
                                       d2, ddeg, c0, bc, bd, BigWt);

  // ---- CSR scan + fused fill/cnt/eattr-permute ----
  k_scan1<<<SCB, 256, 0, stream>>>(cursor, bsum, N_NODES);
  k_scan2<<<1, 256, 0, stream>>>(bsum, SCB);
  k_scan3<<<SCB, 256, 0, stream>>>(cursor, bsum, rowptr, cursor, degf, N_NODES);
  k_fill<<<N_EDGES / 4, 256, 0, stream>>>(rowv, colv, batch, eattr, cursor, crow, eaperm, cnt);

  const int GM = (N_NODES + 63) / 64;      // 782

  Chunks chIter;
  chIter.src[0] = x_b;    chIter.width[0] = 128; chIter.koff[0] = 0;  chIter.scl[0] = 0;
  chIter.src[1] = x_b;    chIter.width[1] = 128; chIter.koff[1] = 64; chIter.scl[1] = 0;
  chIter.src[2] = adjX_b; chIter.width[2] = 128; chIter.koff[2] = 0;  chIter.scl[2] = 0;
  chIter.src[3] = adjX_b; chIter.width[3] = 128; chIter.koff[3] = 64; chIter.scl[3] = 0;
  chIter.src[4] = aggE_b; chIter.width[4] = 64;  chIter.koff[4] = 0;  chIter.scl[4] = 0;
  chIter.src[5] = x_b;    chIter.width[5] = 128; chIter.koff[5] = 0;  chIter.scl[5] = 1;
  chIter.src[6] = x_b;    chIter.width[6] = 128; chIter.koff[6] = 64; chIter.scl[6] = 1;

  // ---- iteration 1 ----
  k_agg<true><<<2048, 256, 0, stream>>>(x_b, eaperm, rowptr, crow, adjX_b, aggE_b);
  gemm_fused3<<<GM, 256, 0, stream>>>(BigWt, bc, bd, degf, chIter, N_NODES, x_b, aggE_b);
  // ---- iteration 2 ----
  k_agg<false><<<2048, 256, 0, stream>>>(x_b, nullptr, rowptr, crow, adjX_b, nullptr);
  gemm_fused3<<<GM, 256, 0, stream>>>(BigWt, bc, bd, degf, chIter, N_NODES, x_b, aggE_b);

  // ---- pooled GlobalModel path (merged cntgemm + pooling) ----
  k_cntpool<<<CGB + (N_NODES + 127) / 128, 256, 0, stream>>>(
      cnt, x_b, Ppart, aggE_b, degf, batch, npool, PaggE, pdeg, N_NODES);

  // ---- head: Ppart reduce + msg_pool + global MLP + final MLP ----
  k_head<<<NB, 256, 0, stream>>>(npool, Ppart, PaggE, pdeg, G1a, G1b, e1,
                                 g2W0, g2b0, g2W1, g2b1, fW0, fb0, fW1, fb1,
                                 (float*)d_out);
}

// Round 16
// 462.726 us; speedup vs baseline: 1.0280x; 1.0280x over previous
//
#include <hip/hip_runtime.h>
#include <hip/hip_bf16.h>

#define N_NODES 50000
#define N_EDGES 400000
#define NB 64
#define SCB 196    // ceil(N_NODES/256)
#define CGB 1024
#define XFB 25000  // N_NODES*128/256
#define EFB 100000 // N_EDGES*64/256

typedef unsigned short u16;
typedef unsigned int u32;
typedef __attribute__((ext_vector_type(8))) short s16x8;
typedef __attribute__((ext_vector_type(4))) float f32x4;

__device__ __forceinline__ u16 f2b(float f) {
  __hip_bfloat16 h = __float2bfloat16(f);
  return *reinterpret_cast<const u16*>(&h);
}
__device__ __forceinline__ float b2f(u16 u) {
  u32 v = ((u32)u) << 16;
  return *reinterpret_cast<const float*>(&v);
}
__device__ __forceinline__ s16x8 scl8(s16x8 v, float dg) {
  s16x8 r;
#pragma unroll
  for (int i = 0; i < 8; ++i) {
    float f = b2f((u16)v[i]) * dg;
    r[i] = (short)f2b(f);
  }
  return r;
}

// ---- merged: x f32->bf16 | eattr f32->bf16 (edge order) | deg histogram ----
__global__ void k_prep(const float* __restrict__ x, u16* __restrict__ xb,
                       const float* __restrict__ eattr, u16* __restrict__ ea_b,
                       const int* __restrict__ colv, int* __restrict__ deg) {
  int b = blockIdx.x;
  if (b < XFB) {
    int i = b * 256 + threadIdx.x;
    xb[i] = f2b(x[i]);
  } else if (b < XFB + EFB) {
    int i = (b - XFB) * 256 + threadIdx.x;
    ea_b[i] = f2b(eattr[i]);
  } else {
    int e = (b - XFB - EFB) * 256 + threadIdx.x;
    if (e < N_EDGES) atomicAdd(&deg[colv[e]], 1);
  }
}

// ---------------- batched small f32 matmuls ----------------
struct MMOp { const float* A; const float* B; const float* add; float* C;
              int lda, r0, ldb, K2, N, rows; };
struct MMBatch { MMOp op[13]; };

__global__ void k_mmb(MMBatch mb) {
  MMOp o = mb.op[blockIdx.y];
  int i = blockIdx.x;
  int n = threadIdx.x;
  if (i >= o.rows || n >= o.N) return;
  float acc = o.add ? o.add[(size_t)i * o.N + n] : 0.f;
  for (int k = 0; k < o.K2; ++k)
    acc = fmaf(o.A[(size_t)(o.r0 + i) * o.lda + k], o.B[(size_t)k * o.ldb + n], acc);
  o.C[(size_t)i * o.N + n] = acc;
}

// ---------------- pack composed weights (bf16, N-major) + bias pack ----------------
__global__ void k_pack_iter(const float* __restrict__ N2a, const float* __restrict__ WadjX,
                            const float* __restrict__ A1, const float* __restrict__ WaggE,
                            const float* __restrict__ C1, const float* __restrict__ Wdegx,
                            const float* __restrict__ B1,
                            const float* __restrict__ d2, const float* __restrict__ ddeg,
                            const float* __restrict__ c0,
                            float* __restrict__ bc, float* __restrict__ bd,
                            u16* __restrict__ Wt) {
  if (blockIdx.x == 336) {
    int t = threadIdx.x;
    if (t < 192) {
      bc[t] = (t < 128) ? d2[t] : 0.f;
      bd[t] = (t < 128) ? ddeg[t] : c0[t - 128];
    }
    return;
  }
  int i = blockIdx.x * 256 + threadIdx.x;
  if (i >= 192 * 448) return;
  int n = i / 448, k = i % 448;
  float v;
  if (k < 128)      v = (n < 128) ? N2a[(size_t)k * 128 + n] : 0.f;
  else if (k < 256) { int kk = k - 128; v = (n < 128) ? WadjX[(size_t)kk * 128 + n] : A1[(size_t)kk * 64 + (n - 128)]; }
  else if (k < 320) { int kk = k - 256; v = (n < 128) ? WaggE[(size_t)kk * 128 + n] : C1[(size_t)kk * 64 + (n - 128)]; }
  else              { int kk = k - 320; v = (n < 128) ? Wdegx[(size_t)kk * 128 + n] : B1[(size_t)kk * 64 + (n - 128)]; }
  Wt[(size_t)n * 448 + k] = f2b(v);
}

// ---------------- 3-phase parallel exclusive scan over deg ----------------
__global__ void k_scan1(const int* __restrict__ deg, int* __restrict__ bsum, int n) {
  __shared__ int red[256];
  int t = threadIdx.x;
  int i = blockIdx.x * 256 + t;
  red[t] = (i < n) ? deg[i] : 0;
  __syncthreads();
  for (int s = 128; s > 0; s >>= 1) {
    if (t < s) red[t] += red[t + s];
    __syncthreads();
  }
  if (t == 0) bsum[blockIdx.x] = red[0];
}

__global__ void k_scan2(int* __restrict__ bsum, int nb) {
  __shared__ int sh[256];
  int t = threadIdx.x;
  sh[t] = (t < nb) ? bsum[t] : 0;
  __syncthreads();
  for (int d = 1; d < 256; d <<= 1) {
    int v = (t >= d) ? sh[t - d] : 0;
    __syncthreads();
    sh[t] += v;
    __syncthreads();
  }
  if (t < nb) bsum[t] = sh[t];
}

__global__ void k_scan3(const int* __restrict__ deg, const int* __restrict__ bsum,
                        int* __restrict__ rowptr, int* __restrict__ cursor,
                        float* __restrict__ degf, int n) {
  __shared__ int sh[256];
  int t = threadIdx.x;
  int i = blockIdx.x * 256 + t;
  int d = (i < n) ? deg[i] : 0;
  sh[t] = d;
  __syncthreads();
  for (int s = 1; s < 256; s <<= 1) {
    int v = (t >= s) ? sh[t - s] : 0;
    __syncthreads();
    sh[t] += v;
    __syncthreads();
  }
  int base = (blockIdx.x > 0) ? bsum[blockIdx.x - 1] : 0;
  int ex = base + sh[t] - d;
  if (i < n) {
    rowptr[i] = ex;
    cursor[i] = ex;
    degf[i] = (float)d;
    if (i == n - 1) rowptr[n] = ex + d;
  }
}

// ---------------- CSR fill + cnt (thread-per-edge, r14-proven) ----------------
__global__ void k_fill(const int* __restrict__ rowv, const int* __restrict__ colv,
                       const int* __restrict__ batch, int* __restrict__ cursor,
                       int* __restrict__ crow, int* __restrict__ ceid,
                       float* __restrict__ cnt) {
  int i = blockIdx.x * 256 + threadIdx.x;
  if (i >= N_EDGES) return;
  int c = colv[i];
  int r = rowv[i];
  int pos = atomicAdd(&cursor[c], 1);
  crow[pos] = r;
  ceid[pos] = i;
  atomicAdd(&cnt[(size_t)r * 64 + batch[c]], 1.0f);
}

// ---------------- merged: cnt-GEMM partials (blocks < CGB) + sorted-batch pooling ----------------
__global__ __launch_bounds__(256)
void k_cntpool(const float* __restrict__ cnt, const u16* __restrict__ xb,
               float* __restrict__ Ppart,
               const u16* __restrict__ aggE, const float* __restrict__ degf,
               const int* __restrict__ batch,
               float* __restrict__ npool, float* __restrict__ PaggE,
               float* __restrict__ pdeg, int n) {
  __shared__ float cs[8][64];
  int t = threadIdx.x;
  if (blockIdx.x < CGB) {
    int c = t & 127, half = t >> 7;
    float acc[32];
#pragma unroll
    for (int q = 0; q < 32; ++q) acc[q] = 0.f;
    int span = (N_NODES + CGB - 1) / CGB;
    int v0 = blockIdx.x * span;
    int v1 = v0 + span; if (v1 > N_NODES) v1 = N_NODES;
    for (int vt = v0; vt < v1; vt += 8) {
      int nv = v1 - vt; if (nv > 8) nv = 8;
      for (int idx = t; idx < nv * 64; idx += 256)
        cs[idx >> 6][idx & 63] = cnt[(size_t)(vt + (idx >> 6)) * 64 + (idx & 63)];
      __syncthreads();
      for (int j = 0; j < nv; ++j) {
        float xv = b2f(xb[(size_t)(vt + j) * 128 + c]);
#pragma unroll
        for (int q = 0; q < 32; ++q) acc[q] = fmaf(cs[j][half * 32 + q], xv, acc[q]);
      }
      __syncthreads();
    }
#pragma unroll
    for (int q = 0; q < 32; ++q)
      Ppart[(size_t)blockIdx.x * 8192 + (size_t)(half * 32 + q) * 128 + c] = acc[q];
  } else {
    int n0 = (blockIdx.x - CGB) * 128;
    if (n0 >= n) return;
    int n1 = n0 + 128; if (n1 > n) n1 = n;
    float acc = 0.f;
    int cur = batch[n0];
    for (int i = n0; i < n1; ++i) {
      int bi = batch[i];
      if (bi != cur) {
        if (t < 128) atomicAdd(&npool[cur * 128 + t], acc);
        else if (t < 192) atomicAdd(&PaggE[cur * 64 + (t - 128)], acc);
        else if (t == 192) atomicAdd(&pdeg[cur], acc);
        acc = 0.f; cur = bi;
      }
      if (t < 128) acc += b2f(xb[(size_t)i * 128 + t]);
      else if (t < 192) acc += b2f(aggE[(size_t)i * 64 + (t - 128)]);
      else if (t == 192) acc += degf[i];
    }
    if (t < 128) atomicAdd(&npool[cur * 128 + t], acc);
    else if (t < 192) atomicAdd(&PaggE[cur * 64 + (t - 128)], acc);
    else if (t == 192) atomicAdd(&pdeg[cur], acc);
  }
}

// ---------------- CSR gather segment-sums (8/4/1; bf16 eattr gather) ----------------
template<bool DOE>
__global__ void k_agg(const u16* __restrict__ xb, const u16* __restrict__ ea_b,
                      const int* __restrict__ rowptr, const int* __restrict__ crow,
                      const int* __restrict__ ceid,
                      u16* __restrict__ outX, u16* __restrict__ outE) {
  int wpb = blockDim.x >> 6;
  int w = blockIdx.x * wpb + (threadIdx.x >> 6);
  int l = threadIdx.x & 63;
  int nw = gridDim.x * wpb;
  for (int v = w; v < N_NODES; v += nw) {
    int s = rowptr[v], e1 = rowptr[v + 1];
    float ax0 = 0.f, ax1 = 0.f, ae = 0.f;
    int i = s;
    for (; i + 7 < e1; i += 8) {
      u32 a[8]; float ev[8];
#pragma unroll
      for (int j = 0; j < 8; ++j)
        a[j] = *reinterpret_cast<const u32*>(&xb[(size_t)crow[i + j] * 128 + l * 2]);
      if (DOE) {
#pragma unroll
        for (int j = 0; j < 8; ++j)
          ev[j] = b2f(ea_b[(size_t)ceid[i + j] * 64 + l]);
      }
#pragma unroll
      for (int j = 0; j < 8; ++j) {
        ax0 += b2f((u16)(a[j] & 0xffff));
        ax1 += b2f((u16)(a[j] >> 16));
        if (DOE) ae += ev[j];
      }
    }
    for (; i + 3 < e1; i += 4) {
      u32 a[4]; float ev[4];
#pragma unroll
      for (int j = 0; j < 4; ++j)
        a[j] = *reinterpret_cast<const u32*>(&xb[(size_t)crow[i + j] * 128 + l * 2]);
      if (DOE) {
#pragma unroll
        for (int j = 0; j < 4; ++j)
          ev[j] = b2f(ea_b[(size_t)ceid[i + j] * 64 + l]);
      }
#pragma unroll
      for (int j = 0; j < 4; ++j) {
        ax0 += b2f((u16)(a[j] & 0xffff));
        ax1 += b2f((u16)(a[j] >> 16));
        if (DOE) ae += ev[j];
      }
    }
    for (; i < e1; ++i) {
      u32 a = *reinterpret_cast<const u32*>(&xb[(size_t)crow[i] * 128 + l * 2]);
      ax0 += b2f((u16)(a & 0xffff));
      ax1 += b2f((u16)(a >> 16));
      if (DOE) ae += b2f(ea_b[(size_t)ceid[i] * 64 + l]);
    }
    u32 pk = ((u32)f2b(ax1) << 16) | (u32)f2b(ax0);
    *reinterpret_cast<u32*>(&outX[(size_t)v * 128 + l * 2]) = pk;
    if (DOE) outE[(size_t)v * 64 + l] = f2b(ae);
  }
}

// ---------------- node GEMM v3: A direct-from-global, B LDS-staged post-barrier ----------------
struct Chunks { const u16* src[7]; int width[7]; int koff[7]; int scl[7]; };

__global__ __launch_bounds__(256)
void gemm_fused3(const u16* __restrict__ Wt,
                 const float* __restrict__ bc, const float* __restrict__ bd,
                 const float* __restrict__ degf, Chunks ch, int M,
                 u16* __restrict__ outb0, u16* __restrict__ outb1)
{
  constexpr int LDA = 72;
  __shared__ u16 Bs[192 * LDA];    // 27648 B; Cs (25600 B) aliases it
  const int t = threadIdx.x;
  const int wv = t >> 6, lane = t & 63, lr = lane & 15, lg = lane >> 4;
  const int bm0 = blockIdx.x * 64;
  const int wb = wv * 16;

  f32x4 acc[12];
#pragma unroll
  for (int f = 0; f < 12; ++f) acc[f] = (f32x4){0.f, 0.f, 0.f, 0.f};

  int arow = bm0 + wb + lr;
  if (arow >= M) arow = M - 1;
  const float dg = degf[arow];

  const int br0 = t >> 2;
  const int bo  = (t & 3) * 16;

#pragma unroll
  for (int c = 0; c < 7; ++c) {
    const u16* ap = ch.src[c] + (size_t)arow * ch.width[c] + ch.koff[c];
    s16x8 af0 = *reinterpret_cast<const s16x8*>(ap + lg * 8);
    s16x8 af1 = *reinterpret_cast<const s16x8*>(ap + 32 + lg * 8);
    if (ch.scl[c]) { af0 = scl8(af0, dg); af1 = scl8(af1, dg); }

    __syncthreads();
#pragma unroll
    for (int p = 0; p < 3; ++p) {
      const u16* bp = Wt + (size_t)(p * 64 + br0) * 448 + c * 64 + bo;
      uint4 b0 = *reinterpret_cast<const uint4*>(bp);
      uint4 b1 = *reinterpret_cast<const uint4*>(bp + 8);
      *reinterpret_cast<uint4*>(&Bs[(p * 64 + br0) * LDA + bo])     = b0;
      *reinterpret_cast<uint4*>(&Bs[(p * 64 + br0) * LDA + bo + 8]) = b1;
    }
    __syncthreads();

#pragma unroll
    for (int f = 0; f < 12; ++f) {
      s16x8 bf = *reinterpret_cast<const s16x8*>(&Bs[(f * 16 + lr) * LDA + lg * 8]);
      acc[f] = __builtin_amdgcn_mfma_f32_16x16x32_bf16(af0, bf, acc[f], 0, 0, 0);
    }
#pragma unroll
    for (int f = 0; f < 12; ++f) {
      s16x8 bf = *reinterpret_cast<const s16x8*>(&Bs[(f * 16 + lr) * LDA + 32 + lg * 8]);
      acc[f] = __builtin_amdgcn_mfma_f32_16x16x32_bf16(af1, bf, acc[f], 0, 0, 0);
    }
  }

  __syncthreads();
  u16 (*Cs)[200] = reinterpret_cast<u16(*)[200]>(Bs);
#pragma unroll
  for (int rr = 0; rr < 4; ++rr) {
    int lrow = wb + lg * 4 + rr;
    int grow = bm0 + lrow;
    float dgr = degf[(grow < M) ? grow : (M - 1)];
#pragma unroll
    for (int f = 0; f < 12; ++f) {
      int col = f * 16 + lr;
      float v = acc[f][rr] + bc[col] + dgr * bd[col];
      Cs[lrow][col] = f2b(v);
    }
  }
  __syncthreads();

#pragma unroll
  for (int p = 0; p < 4; ++p) {
    int r = p * 16 + (t >> 4), c = (t & 15) * 8;
    if (bm0 + r < M)
      *reinterpret_cast<uint4*>(&outb0[(size_t)(bm0 + r) * 128 + c]) =
          *reinterpret_cast<const uint4*>(&Cs[r][c]);
  }
#pragma unroll
  for (int p = 0; p < 2; ++p) {
    int r = p * 32 + (t >> 3), c = (t & 7) * 8;
    if (bm0 + r < M)
      *reinterpret_cast<uint4*>(&outb1[(size_t)(bm0 + r) * 64 + c]) =
          *reinterpret_cast<const uint4*>(&Cs[r][128 + c]);
  }
}

// ---------------- head: Ppart-reduce + msg_pool + global MLP + final MLP ----------------
__global__ void k_head(const float* __restrict__ npool, const float* __restrict__ Ppart,
                       const float* __restrict__ PaggE, const float* __restrict__ pdeg,
                       const float* __restrict__ G1a, const float* __restrict__ G1b,
                       const float* __restrict__ e1,
                       const float* __restrict__ g2W0, const float* __restrict__ g2b0,
                       const float* __restrict__ g2W1, const float* __restrict__ g2b1,
                       const float* __restrict__ fW0, const float* __restrict__ fb0,
                       const float* __restrict__ fW1, const float* __restrict__ fb1,
                       float* __restrict__ out) {
  __shared__ float padj[128], r0[256], r1[128], r2[128], r3[256], red[256];
  int b = blockIdx.x, t = threadIdx.x;
  if (t < 128) {
    float s = 0.f;
    for (int j = 0; j < CGB; ++j) s += Ppart[(size_t)j * 8192 + (size_t)b * 128 + t];
    padj[t] = s;
  }
  __syncthreads();
  if (t < 128) {
    float a = pdeg[b] * e1[t];
    for (int k = 0; k < 128; ++k) a = fmaf(padj[k], G1a[(size_t)k * 128 + t], a);
    for (int k = 0; k < 64;  ++k) a = fmaf(PaggE[(size_t)b * 64 + k],  G1b[(size_t)k * 128 + t], a);
    r0[128 + t] = a;
    r0[t] = npool[(size_t)b * 128 + t];
  }
  __syncthreads();
  if (t < 128) {
    float a = g2b0[t];
    for (int k = 0; k < 256; ++k) a = fmaf(r0[k], g2W0[(size_t)k * 128 + t], a);
    r1[t] = a;
  }
  __syncthreads();
  if (t < 128) {
    float a = g2b1[t];
    for (int k = 0; k < 128; ++k) a = fmaf(r1[k], g2W1[(size_t)k * 128 + t], a);
    r2[t] = a;
  }
  __syncthreads();
  {
    float a = fb0[t];
    for (int k = 0; k < 128; ++k) a = fmaf(r2[k], fW0[(size_t)k * 256 + t], a);
    r3[t] = a;
  }
  __syncthreads();
  red[t] = r3[t] * fW1[t];
  __syncthreads();
  for (int s = 128; s > 0; s >>= 1) {
    if (t < s) red[t] += red[t + s];
    __syncthreads();
  }
  if (t == 0) out[b] = red[0] + fb1[0];
}

extern "C" void kernel_launch(void* const* d_in, const int* in_sizes, int n_in,
                              void* d_out, int out_size, void* d_ws, size_t ws_size,
                              hipStream_t stream) {
  const float* x     = (const float*)d_in[0];
  const int*   eidx  = (const int*)d_in[1];
  const float* eattr = (const float*)d_in[2];
  const int*   batch = (const int*)d_in[3];
  const float* eW0 = (const float*)d_in[4];  const float* eb0 = (const float*)d_in[5];
  const float* eW1 = (const float*)d_in[6];  const float* eb1 = (const float*)d_in[7];
  const float* n1W0 = (const float*)d_in[8]; const float* n1b0 = (const float*)d_in[9];
  const float* n1W1 = (const float*)d_in[10];const float* n1b1 = (const float*)d_in[11];
  const float* n2W0 = (const float*)d_in[12];const float* n2b0 = (const float*)d_in[13];
  const float* n2W1 = (const float*)d_in[14];const float* n2b1 = (const float*)d_in[15];
  const float* g1W0 = (const float*)d_in[16];const float* g1b0 = (const float*)d_in[17];
  const float* g1W1 = (const float*)d_in[18];const float* g1b1 = (const float*)d_in[19];
  const float* g2W0 = (const float*)d_in[20];const float* g2b0 = (const float*)d_in[21];
  const float* g2W1 = (const float*)d_in[22];const float* g2b1 = (const float*)d_in[23];
  const float* fW0 = (const float*)d_in[24]; const float* fb0 = (const float*)d_in[25];
  const float* fW1 = (const float*)d_in[26]; const float* fb1 = (const float*)d_in[27];

  const int* rowv = eidx;
  const int* colv = eidx + N_EDGES;

  char* ws = (char*)d_ws;
  size_t off = 0;
  auto alloc = [&](size_t bytes) -> void* {
    void* p = ws + off; off = (off + bytes + 255) & ~(size_t)255; return p;
  };
  u16*   x_b    = (u16*)alloc((size_t)N_NODES * 128 * 2);
  u16*   adjX_b = (u16*)alloc((size_t)N_NODES * 128 * 2);
  u16*   aggE_b = (u16*)alloc((size_t)N_NODES * 64 * 2);
  u16*   ea_b   = (u16*)alloc((size_t)N_EDGES * 64 * 2);
  float* degf   = (float*)alloc((size_t)N_NODES * 4);
  int*   rowptr = (int*)alloc((size_t)(N_NODES + 1) * 4);
  int*   crow   = (int*)alloc((size_t)N_EDGES * 4);
  int*   ceid   = (int*)alloc((size_t)N_EDGES * 4);
  int*   bsum   = (int*)alloc((size_t)256 * 4);
  float* Ppart  = (float*)alloc((size_t)CGB * 8192 * 4);
  // ---- zeroed region (single memset) ----
  char*  zstart = ws + off;
  int*   cursor = (int*)alloc((size_t)N_NODES * 4);
  float* cnt    = (float*)alloc((size_t)N_NODES * 64 * 4);
  float* npool  = (float*)alloc((size_t)NB * 128 * 4);
  float* PaggE  = (float*)alloc((size_t)NB * 64 * 4);
  float* pdeg   = (float*)alloc((size_t)NB * 4);
  size_t zbytes = (size_t)((ws + off) - zstart);
  // ---- f32 weight-composition scratch ----
  float* N1a   = (float*)alloc(128 * 128 * 4);
  float* N1b   = (float*)alloc(64 * 128 * 4);
  float* N2a   = (float*)alloc(128 * 128 * 4);
  float* N2b   = (float*)alloc(128 * 128 * 4);
  float* A1    = (float*)alloc(128 * 64 * 4);
  float* B1    = (float*)alloc(128 * 64 * 4);
  float* C1    = (float*)alloc(64 * 64 * 4);
  float* G1a   = (float*)alloc(128 * 128 * 4);
  float* G1b   = (float*)alloc(64 * 128 * 4);
  float* T1    = (float*)alloc(64 * 128 * 4);
  float* U1    = (float*)alloc(128 * 128 * 4);
  float* WadjX = (float*)alloc(128 * 128 * 4);
  float* WaggE = (float*)alloc(64 * 128 * 4);
  float* Wdegx = (float*)alloc(128 * 128 * 4);
  float* c0    = (float*)alloc(64 * 4);
  float* d1    = (float*)alloc(128 * 4);
  float* d2    = (float*)alloc(128 * 4);
  float* q2    = (float*)alloc(128 * 4);
  float* ddeg  = (float*)alloc(128 * 4);
  float* e1    = (float*)alloc(128 * 4);
  float* bc    = (float*)alloc(192 * 4);
  float* bd    = (float*)alloc(192 * 4);
  u16*   BigWt = (u16*)alloc((size_t)192 * 448 * 2);
  (void)ws_size; (void)in_sizes; (void)n_in; (void)out_size;

  // ---- one memset for everything needing zeros ----
  hipMemsetAsync(zstart, 0, zbytes, stream);

  // x -> bf16 | eattr -> bf16 | deg histogram (merged)
  k_prep<<<XFB + EFB + (N_EDGES + 255) / 256, 256, 0, stream>>>(x, x_b, eattr, ea_b, colv, cursor);

  // ---- weight composition, level-batched (3 levels) ----
  {
    MMBatch L1{};
    L1.op[0]  = {n1W0, n1W1, nullptr, N1a, 128, 0,   128, 128, 128, 128};
    L1.op[1]  = {n1W0, n1W1, nullptr, N1b, 128, 128, 128, 128, 128, 64};
    L1.op[2]  = {n2W0, n2W1, nullptr, N2a, 128, 0,   128, 128, 128, 128};
    L1.op[3]  = {n2W0, n2W1, nullptr, N2b, 128, 128, 128, 128, 128, 128};
    L1.op[4]  = {eW0,  eW1,  nullptr, A1,  128, 0,   64,  128, 64,  128};
    L1.op[5]  = {eW0,  eW1,  nullptr, B1,  128, 128, 64,  128, 64,  128};
    L1.op[6]  = {eW0,  eW1,  nullptr, C1,  128, 256, 64,  128, 64,  64};
    L1.op[7]  = {g1W0, g1W1, nullptr, G1a, 128, 0,   128, 128, 128, 128};
    L1.op[8]  = {g1W0, g1W1, nullptr, G1b, 128, 128, 128, 128, 128, 64};
    L1.op[9]  = {eb0,  eW1,  eb1,     c0,  128, 0,   64,  128, 64,  1};
    L1.op[10] = {n1b0, n1W1, n1b1,    d1,  128, 0,   128, 128, 128, 1};
    L1.op[11] = {n2b0, n2W1, n2b1,    d2,  128, 0,   128, 128, 128, 1};
    L1.op[12] = {g1b0, g1W1, g1b1,    e1,  128, 0,   128, 128, 128, 1};
    k_mmb<<<dim3(128, 13), 128, 0, stream>>>(L1);

    MMBatch L2{};
    L2.op[0] = {N1b, N2b, nullptr, T1, 128, 0, 128, 128, 128, 64};
    L2.op[1] = {N1a, N2b, nullptr, U1, 128, 0, 128, 128, 128, 128};
    L2.op[2] = {c0,  N1b, d1,      q2, 64,  0, 128, 64,  128, 1};
    for (int j = 3; j < 13; ++j) L2.op[j] = {nullptr, nullptr, nullptr, nullptr, 0, 0, 0, 0, 0, 0};
    k_mmb<<<dim3(128, 3), 128, 0, stream>>>(L2);

    MMBatch L3{};
    L3.op[0] = {A1, T1, U1,      WadjX, 64,  0, 128, 64,  128, 128};
    L3.op[1] = {C1, T1, nullptr, WaggE, 64,  0, 128, 64,  128, 64};
    L3.op[2] = {B1, T1, nullptr, Wdegx, 64,  0, 128, 64,  128, 128};
    L3.op[3] = {q2, N2b, nullptr, ddeg, 128, 0, 128, 128, 128, 1};
    for (int j = 4; j < 13; ++j) L3.op[j] = {nullptr, nullptr, nullptr, nullptr, 0, 0, 0, 0, 0, 0};
    k_mmb<<<dim3(128, 4), 128, 0, stream>>>(L3);
  }
  k_pack_iter<<<337, 256, 0, stream>>>(N2a, WadjX, A1, WaggE, C1, Wdegx, B1,
                                       d2, ddeg, c0, bc, bd, BigWt);

  // ---- CSR scan + fill/cnt ----
  k_scan1<<<SCB, 256, 0, stream>>>(cursor, bsum, N_NODES);
  k_scan2<<<1, 256, 0, stream>>>(bsum, SCB);
  k_scan3<<<SCB, 256, 0, stream>>>(cursor, bsum, rowptr, cursor, degf, N_NODES);
  k_fill<<<(N_EDGES + 255) / 256, 256, 0, stream>>>(rowv, colv, batch, cursor, crow, ceid, cnt);

  const int GM = (N_NODES + 63) / 64;      // 782

  Chunks chIter;
  chIter.src[0] = x_b;    chIter.width[0] = 128; chIter.koff[0] = 0;  chIter.scl[0] = 0;
  chIter.src[1] = x_b;    chIter.width[1] = 128; chIter.koff[1] = 64; chIter.scl[1] = 0;
  chIter.src[2] = adjX_b; chIter.width[2] = 128; chIter.koff[2] = 0;  chIter.scl[2] = 0;
  chIter.src[3] = adjX_b; chIter.width[3] = 128; chIter.koff[3] = 64; chIter.scl[3] = 0;
  chIter.src[4] = aggE_b; chIter.width[4] = 64;  chIter.koff[4] = 0;  chIter.scl[4] = 0;
  chIter.src[5] = x_b;    chIter.width[5] = 128; chIter.koff[5] = 0;  chIter.scl[5] = 1;
  chIter.src[6] = x_b;    chIter.width[6] = 128; chIter.koff[6] = 64; chIter.scl[6] = 1;

  // ---- iteration 1 ----
  k_agg<true><<<2048, 256, 0, stream>>>(x_b, ea_b, rowptr, crow, ceid, adjX_b, aggE_b);
  gemm_fused3<<<GM, 256, 0, stream>>>(BigWt, bc, bd, degf, chIter, N_NODES, x_b, aggE_b);
  // ---- iteration 2 ----
  k_agg<false><<<2048, 256, 0, stream>>>(x_b, nullptr, rowptr, crow, ceid, adjX_b, nullptr);
  gemm_fused3<<<GM, 256, 0, stream>>>(BigWt, bc, bd, degf, chIter, N_NODES, x_b, aggE_b);

  // ---- pooled GlobalModel path (merged cntgemm + pooling) ----
  k_cntpool<<<CGB + (N_NODES + 127) / 128, 256, 0, stream>>>(
      cnt, x_b, Ppart, aggE_b, degf, batch, npool, PaggE, pdeg, N_NODES);

  // ---- head: Ppart reduce + msg_pool + global MLP + final MLP ----
  k_head<<<NB, 256, 0, stream>>>(npool, Ppart, PaggE, pdeg, G1a, G1b, e1,
                                 g2W0, g2b0, g2W1, g2b1, fW0, fb0, fW1, fb1,
                                 (float*)d_out);
}

// Round 17
// 430.207 us; speedup vs baseline: 1.1057x; 1.0756x over previous
//
#include <hip/hip_runtime.h>
#include <hip/hip_bf16.h>

#define N_NODES 50000
#define N_EDGES 400000
#define NB 64
#define SCB 196    // ceil(N_NODES/256)
#define CGB 1024
#define XF8 3125   // N_NODES*128/(256*8)

typedef unsigned short u16;
typedef unsigned int u32;
typedef __attribute__((ext_vector_type(8))) short s16x8;
typedef __attribute__((ext_vector_type(4))) float f32x4;

__device__ __forceinline__ u16 f2b(float f) {
  __hip_bfloat16 h = __float2bfloat16(f);
  return *reinterpret_cast<const u16*>(&h);
}
__device__ __forceinline__ float b2f(u16 u) {
  u32 v = ((u32)u) << 16;
  return *reinterpret_cast<const float*>(&v);
}
__device__ __forceinline__ s16x8 scl8(s16x8 v, float dg) {
  s16x8 r;
#pragma unroll
  for (int i = 0; i < 8; ++i) {
    float f = b2f((u16)v[i]) * dg;
    r[i] = (short)f2b(f);
  }
  return r;
}

// ---- merged: x f32->bf16 (vectorized, 8 elems/thread) + deg histogram ----
__global__ void k_prep(const float* __restrict__ x, u16* __restrict__ xb,
                       const int* __restrict__ colv, int* __restrict__ deg) {
  int b = blockIdx.x;
  if (b < XF8) {
    int i = (b * 256 + threadIdx.x) * 8;
    float4 v0 = *reinterpret_cast<const float4*>(&x[i]);
    float4 v1 = *reinterpret_cast<const float4*>(&x[i + 4]);
    u16 o[8] = {f2b(v0.x), f2b(v0.y), f2b(v0.z), f2b(v0.w),
                f2b(v1.x), f2b(v1.y), f2b(v1.z), f2b(v1.w)};
    *reinterpret_cast<uint4*>(&xb[i]) = *reinterpret_cast<const uint4*>(o);
  } else {
    int e = (b - XF8) * 256 + threadIdx.x;
    if (e < N_EDGES) atomicAdd(&deg[colv[e]], 1);
  }
}

// ---------------- batched small f32 matmuls ----------------
struct MMOp { const float* A; const float* B; const float* add; float* C;
              int lda, r0, ldb, K2, N, rows; };
struct MMBatch { MMOp op[13]; };

__global__ void k_mmb(MMBatch mb) {
  MMOp o = mb.op[blockIdx.y];
  int i = blockIdx.x;
  int n = threadIdx.x;
  if (i >= o.rows || n >= o.N) return;
  float acc = o.add ? o.add[(size_t)i * o.N + n] : 0.f;
  for (int k = 0; k < o.K2; ++k)
    acc = fmaf(o.A[(size_t)(o.r0 + i) * o.lda + k], o.B[(size_t)k * o.ldb + n], acc);
  o.C[(size_t)i * o.N + n] = acc;
}

// ---------------- pack composed weights (bf16, N-major) + bias pack ----------------
__global__ void k_pack_iter(const float* __restrict__ N2a, const float* __restrict__ WadjX,
                            const float* __restrict__ A1, const float* __restrict__ WaggE,
                            const float* __restrict__ C1, const float* __restrict__ Wdegx,
                            const float* __restrict__ B1,
                            const float* __restrict__ d2, const float* __restrict__ ddeg,
                            const float* __restrict__ c0,
                            float* __restrict__ bc, float* __restrict__ bd,
                            u16* __restrict__ Wt) {
  if (blockIdx.x == 336) {
    int t = threadIdx.x;
    if (t < 192) {
      bc[t] = (t < 128) ? d2[t] : 0.f;
      bd[t] = (t < 128) ? ddeg[t] : c0[t - 128];
    }
    return;
  }
  int i = blockIdx.x * 256 + threadIdx.x;
  if (i >= 192 * 448) return;
  int n = i / 448, k = i % 448;
  float v;
  if (k < 128)      v = (n < 128) ? N2a[(size_t)k * 128 + n] : 0.f;
  else if (k < 256) { int kk = k - 128; v = (n < 128) ? WadjX[(size_t)kk * 128 + n] : A1[(size_t)kk * 64 + (n - 128)]; }
  else if (k < 320) { int kk = k - 256; v = (n < 128) ? WaggE[(size_t)kk * 128 + n] : C1[(size_t)kk * 64 + (n - 128)]; }
  else              { int kk = k - 320; v = (n < 128) ? Wdegx[(size_t)kk * 128 + n] : B1[(size_t)kk * 64 + (n - 128)]; }
  Wt[(size_t)n * 448 + k] = f2b(v);
}

// ---------------- 3-phase parallel exclusive scan over deg ----------------
__global__ void k_scan1(const int* __restrict__ deg, int* __restrict__ bsum, int n) {
  __shared__ int red[256];
  int t = threadIdx.x;
  int i = blockIdx.x * 256 + t;
  red[t] = (i < n) ? deg[i] : 0;
  __syncthreads();
  for (int s = 128; s > 0; s >>= 1) {
    if (t < s) red[t] += red[t + s];
    __syncthreads();
  }
  if (t == 0) bsum[blockIdx.x] = red[0];
}

__global__ void k_scan2(int* __restrict__ bsum, int nb) {
  __shared__ int sh[256];
  int t = threadIdx.x;
  sh[t] = (t < nb) ? bsum[t] : 0;
  __syncthreads();
  for (int d = 1; d < 256; d <<= 1) {
    int v = (t >= d) ? sh[t - d] : 0;
    __syncthreads();
    sh[t] += v;
    __syncthreads();
  }
  if (t < nb) bsum[t] = sh[t];
}

__global__ void k_scan3(const int* __restrict__ deg, const int* __restrict__ bsum,
                        int* __restrict__ rowptr, int* __restrict__ cursor,
                        float* __restrict__ degf, int n) {
  __shared__ int sh[256];
  int t = threadIdx.x;
  int i = blockIdx.x * 256 + t;
  int d = (i < n) ? deg[i] : 0;
  sh[t] = d;
  __syncthreads();
  for (int s = 1; s < 256; s <<= 1) {
    int v = (t >= s) ? sh[t - s] : 0;
    __syncthreads();
    sh[t] += v;
    __syncthreads();
  }
  int base = (blockIdx.x > 0) ? bsum[blockIdx.x - 1] : 0;
  int ex = base + sh[t] - d;
  if (i < n) {
    rowptr[i] = ex;
    cursor[i] = ex;
    degf[i] = (float)d;
    if (i == n - 1) rowptr[n] = ex + d;
  }
}

// ---------------- CSR fill + cnt (thread-per-edge) ----------------
__global__ void k_fill(const int* __restrict__ rowv, const int* __restrict__ colv,
                       const int* __restrict__ batch, int* __restrict__ cursor,
                       int* __restrict__ crow, int* __restrict__ ceid,
                       float* __restrict__ cnt) {
  int i = blockIdx.x * 256 + threadIdx.x;
  if (i >= N_EDGES) return;
  int c = colv[i];
  int r = rowv[i];
  int pos = atomicAdd(&cursor[c], 1);
  crow[pos] = r;
  ceid[pos] = i;
  atomicAdd(&cnt[(size_t)r * 64 + batch[c]], 1.0f);
}

// ---------------- merged: cnt-GEMM partials (blocks < CGB) + sorted-batch pooling ----------------
__global__ __launch_bounds__(256)
void k_cntpool(const float* __restrict__ cnt, const u16* __restrict__ xb,
               float* __restrict__ Ppart,
               const u16* __restrict__ aggE, const float* __restrict__ degf,
               const int* __restrict__ batch,
               float* __restrict__ npool, float* __restrict__ PaggE,
               float* __restrict__ pdeg, int n) {
  __shared__ float cs[8][64];
  int t = threadIdx.x;
  if (blockIdx.x < CGB) {
    int c = t & 127, half = t >> 7;
    float acc[32];
#pragma unroll
    for (int q = 0; q < 32; ++q) acc[q] = 0.f;
    int span = (N_NODES + CGB - 1) / CGB;
    int v0 = blockIdx.x * span;
    int v1 = v0 + span; if (v1 > N_NODES) v1 = N_NODES;
    for (int vt = v0; vt < v1; vt += 8) {
      int nv = v1 - vt; if (nv > 8) nv = 8;
      for (int idx = t; idx < nv * 64; idx += 256)
        cs[idx >> 6][idx & 63] = cnt[(size_t)(vt + (idx >> 6)) * 64 + (idx & 63)];
      __syncthreads();
      for (int j = 0; j < nv; ++j) {
        float xv = b2f(xb[(size_t)(vt + j) * 128 + c]);
#pragma unroll
        for (int q = 0; q < 32; ++q) acc[q] = fmaf(cs[j][half * 32 + q], xv, acc[q]);
      }
      __syncthreads();
    }
#pragma unroll
    for (int q = 0; q < 32; ++q)
      Ppart[(size_t)blockIdx.x * 8192 + (size_t)(half * 32 + q) * 128 + c] = acc[q];
  } else {
    int n0 = (blockIdx.x - CGB) * 128;
    if (n0 >= n) return;
    int n1 = n0 + 128; if (n1 > n) n1 = n;
    float acc = 0.f;
    int cur = batch[n0];
    for (int i = n0; i < n1; ++i) {
      int bi = batch[i];
      if (bi != cur) {
        if (t < 128) atomicAdd(&npool[cur * 128 + t], acc);
        else if (t < 192) atomicAdd(&PaggE[cur * 64 + (t - 128)], acc);
        else if (t == 192) atomicAdd(&pdeg[cur], acc);
        acc = 0.f; cur = bi;
      }
      if (t < 128) acc += b2f(xb[(size_t)i * 128 + t]);
      else if (t < 192) acc += b2f(aggE[(size_t)i * 64 + (t - 128)]);
      else if (t == 192) acc += degf[i];
    }
    if (t < 128) atomicAdd(&npool[cur * 128 + t], acc);
    else if (t < 192) atomicAdd(&PaggE[cur * 64 + (t - 128)], acc);
    else if (t == 192) atomicAdd(&pdeg[cur], acc);
  }
}

// ---------------- CSR gather segment-sums (8/4/1 unrolled; f32 eattr via ceid) ----------------
template<bool DOE>
__global__ void k_agg(const u16* __restrict__ xb, const float* __restrict__ eaf,
                      const int* __restrict__ rowptr, const int* __restrict__ crow,
                      const int* __restrict__ ceid,
                      u16* __restrict__ outX, u16* __restrict__ outE) {
  int wpb = blockDim.x >> 6;
  int w = blockIdx.x * wpb + (threadIdx.x >> 6);
  int l = threadIdx.x & 63;
  int nw = gridDim.x * wpb;
  for (int v = w; v < N_NODES; v += nw) {
    int s = rowptr[v], e1 = rowptr[v + 1];
    float ax0 = 0.f, ax1 = 0.f, ae = 0.f;
    int i = s;
    for (; i + 7 < e1; i += 8) {
      u32 a[8]; float ev[8];
#pragma unroll
      for (int j = 0; j < 8; ++j)
        a[j] = *reinterpret_cast<const u32*>(&xb[(size_t)crow[i + j] * 128 + l * 2]);
      if (DOE) {
#pragma unroll
        for (int j = 0; j < 8; ++j)
          ev[j] = eaf[(size_t)ceid[i + j] * 64 + l];
      }
#pragma unroll
      for (int j = 0; j < 8; ++j) {
        ax0 += b2f((u16)(a[j] & 0xffff));
        ax1 += b2f((u16)(a[j] >> 16));
        if (DOE) ae += ev[j];
      }
    }
    for (; i + 3 < e1; i += 4) {
      u32 a[4]; float ev[4];
#pragma unroll
      for (int j = 0; j < 4; ++j)
        a[j] = *reinterpret_cast<const u32*>(&xb[(size_t)crow[i + j] * 128 + l * 2]);
      if (DOE) {
#pragma unroll
        for (int j = 0; j < 4; ++j)
          ev[j] = eaf[(size_t)ceid[i + j] * 64 + l];
      }
#pragma unroll
      for (int j = 0; j < 4; ++j) {
        ax0 += b2f((u16)(a[j] & 0xffff));
        ax1 += b2f((u16)(a[j] >> 16));
        if (DOE) ae += ev[j];
      }
    }
    for (; i < e1; ++i) {
      u32 a = *reinterpret_cast<const u32*>(&xb[(size_t)crow[i] * 128 + l * 2]);
      ax0 += b2f((u16)(a & 0xffff));
      ax1 += b2f((u16)(a >> 16));
      if (DOE) ae += eaf[(size_t)ceid[i] * 64 + l];
    }
    u32 pk = ((u32)f2b(ax1) << 16) | (u32)f2b(ax0);
    *reinterpret_cast<u32*>(&outX[(size_t)v * 128 + l * 2]) = pk;
    if (DOE) outE[(size_t)v * 64 + l] = f2b(ae);
  }
}

// ---------------- node GEMM v3: A direct-from-global, B LDS-staged post-barrier ----------------
struct Chunks { const u16* src[7]; int width[7]; int koff[7]; int scl[7]; };

__global__ __launch_bounds__(256)
void gemm_fused3(const u16* __restrict__ Wt,
                 const float* __restrict__ bc, const float* __restrict__ bd,
                 const float* __restrict__ degf, Chunks ch, int M,
                 u16* __restrict__ outb0, u16* __restrict__ outb1)
{
  constexpr int LDA = 72;
  __shared__ u16 Bs[192 * LDA];    // 27648 B; Cs (25600 B) aliases it
  const int t = threadIdx.x;
  const int wv = t >> 6, lane = t & 63, lr = lane & 15, lg = lane >> 4;
  const int bm0 = blockIdx.x * 64;
  const int wb = wv * 16;

  f32x4 acc[12];
#pragma unroll
  for (int f = 0; f < 12; ++f) acc[f] = (f32x4){0.f, 0.f, 0.f, 0.f};

  int arow = bm0 + wb + lr;
  if (arow >= M) arow = M - 1;
  const float dg = degf[arow];

  const int br0 = t >> 2;
  const int bo  = (t & 3) * 16;

#pragma unroll
  for (int c = 0; c < 7; ++c) {
    const u16* ap = ch.src[c] + (size_t)arow * ch.width[c] + ch.koff[c];
    s16x8 af0 = *reinterpret_cast<const s16x8*>(ap + lg * 8);
    s16x8 af1 = *reinterpret_cast<const s16x8*>(ap + 32 + lg * 8);
    if (ch.scl[c]) { af0 = scl8(af0, dg); af1 = scl8(af1, dg); }

    __syncthreads();
#pragma unroll
    for (int p = 0; p < 3; ++p) {
      const u16* bp = Wt + (size_t)(p * 64 + br0) * 448 + c * 64 + bo;
      uint4 b0 = *reinterpret_cast<const uint4*>(bp);
      uint4 b1 = *reinterpret_cast<const uint4*>(bp + 8);
      *reinterpret_cast<uint4*>(&Bs[(p * 64 + br0) * LDA + bo])     = b0;
      *reinterpret_cast<uint4*>(&Bs[(p * 64 + br0) * LDA + bo + 8]) = b1;
    }
    __syncthreads();

#pragma unroll
    for (int f = 0; f < 12; ++f) {
      s16x8 bf = *reinterpret_cast<const s16x8*>(&Bs[(f * 16 + lr) * LDA + lg * 8]);
      acc[f] = __builtin_amdgcn_mfma_f32_16x16x32_bf16(af0, bf, acc[f], 0, 0, 0);
    }
#pragma unroll
    for (int f = 0; f < 12; ++f) {
      s16x8 bf = *reinterpret_cast<const s16x8*>(&Bs[(f * 16 + lr) * LDA + 32 + lg * 8]);
      acc[f] = __builtin_amdgcn_mfma_f32_16x16x32_bf16(af1, bf, acc[f], 0, 0, 0);
    }
  }

  __syncthreads();
  u16 (*Cs)[200] = reinterpret_cast<u16(*)[200]>(Bs);
#pragma unroll
  for (int rr = 0; rr < 4; ++rr) {
    int lrow = wb + lg * 4 + rr;
    int grow = bm0 + lrow;
    float dgr = degf[(grow < M) ? grow : (M - 1)];
#pragma unroll
    for (int f = 0; f < 12; ++f) {
      int col = f * 16 + lr;
      float v = acc[f][rr] + bc[col] + dgr * bd[col];
      Cs[lrow][col] = f2b(v);
    }
  }
  __syncthreads();

#pragma unroll
  for (int p = 0; p < 4; ++p) {
    int r = p * 16 + (t >> 4), c = (t & 15) * 8;
    if (bm0 + r < M)
      *reinterpret_cast<uint4*>(&outb0[(size_t)(bm0 + r) * 128 + c]) =
          *reinterpret_cast<const uint4*>(&Cs[r][c]);
  }
#pragma unroll
  for (int p = 0; p < 2; ++p) {
    int r = p * 32 + (t >> 3), c = (t & 7) * 8;
    if (bm0 + r < M)
      *reinterpret_cast<uint4*>(&outb1[(size_t)(bm0 + r) * 64 + c]) =
          *reinterpret_cast<const uint4*>(&Cs[r][128 + c]);
  }
}

// ---------------- head: Ppart-reduce + msg_pool + global MLP + final MLP ----------------
__global__ void k_head(const float* __restrict__ npool, const float* __restrict__ Ppart,
                       const float* __restrict__ PaggE, const float* __restrict__ pdeg,
                       const float* __restrict__ G1a, const float* __restrict__ G1b,
                       const float* __restrict__ e1,
                       const float* __restrict__ g2W0, const float* __restrict__ g2b0,
                       const float* __restrict__ g2W1, const float* __restrict__ g2b1,
                       const float* __restrict__ fW0, const float* __restrict__ fb0,
                       const float* __restrict__ fW1, const float* __restrict__ fb1,
                       float* __restrict__ out) {
  __shared__ float padj[128], r0[256], r1[128], r2[128], r3[256], red[256];
  int b = blockIdx.x, t = threadIdx.x;
  if (t < 128) {
    float s = 0.f;
    for (int j = 0; j < CGB; ++j) s += Ppart[(size_t)j * 8192 + (size_t)b * 128 + t];
    padj[t] = s;
  }
  __syncthreads();
  if (t < 128) {
    float a = pdeg[b] * e1[t];
    for (int k = 0; k < 128; ++k) a = fmaf(padj[k], G1a[(size_t)k * 128 + t], a);
    for (int k = 0; k < 64;  ++k) a = fmaf(PaggE[(size_t)b * 64 + k],  G1b[(size_t)k * 128 + t], a);
    r0[128 + t] = a;
    r0[t] = npool[(size_t)b * 128 + t];
  }
  __syncthreads();
  if (t < 128) {
    float a = g2b0[t];
    for (int k = 0; k < 256; ++k) a = fmaf(r0[k], g2W0[(size_t)k * 128 + t], a);
    r1[t] = a;
  }
  __syncthreads();
  if (t < 128) {
    float a = g2b1[t];
    for (int k = 0; k < 128; ++k) a = fmaf(r1[k], g2W1[(size_t)k * 128 + t], a);
    r2[t] = a;
  }
  __syncthreads();
  {
    float a = fb0[t];
    for (int k = 0; k < 128; ++k) a = fmaf(r2[k], fW0[(size_t)k * 256 + t], a);
    r3[t] = a;
  }
  __syncthreads();
  red[t] = r3[t] * fW1[t];
  __syncthreads();
  for (int s = 128; s > 0; s >>= 1) {
    if (t < s) red[t] += red[t + s];
    __syncthreads();
  }
  if (t == 0) out[b] = red[0] + fb1[0];
}

extern "C" void kernel_launch(void* const* d_in, const int* in_sizes, int n_in,
                              void* d_out, int out_size, void* d_ws, size_t ws_size,
                              hipStream_t stream) {
  const float* x     = (const float*)d_in[0];
  const int*   eidx  = (const int*)d_in[1];
  const float* eattr = (const float*)d_in[2];
  const int*   batch = (const int*)d_in[3];
  const float* eW0 = (const float*)d_in[4];  const float* eb0 = (const float*)d_in[5];
  const float* eW1 = (const float*)d_in[6];  const float* eb1 = (const float*)d_in[7];
  const float* n1W0 = (const float*)d_in[8]; const float* n1b0 = (const float*)d_in[9];
  const float* n1W1 = (const float*)d_in[10];const float* n1b1 = (const float*)d_in[11];
  const float* n2W0 = (const float*)d_in[12];const float* n2b0 = (const float*)d_in[13];
  const float* n2W1 = (const float*)d_in[14];const float* n2b1 = (const float*)d_in[15];
  const float* g1W0 = (const float*)d_in[16];const float* g1b0 = (const float*)d_in[17];
  const float* g1W1 = (const float*)d_in[18];const float* g1b1 = (const float*)d_in[19];
  const float* g2W0 = (const float*)d_in[20];const float* g2b0 = (const float*)d_in[21];
  const float* g2W1 = (const float*)d_in[22];const float* g2b1 = (const float*)d_in[23];
  const float* fW0 = (const float*)d_in[24]; const float* fb0 = (const float*)d_in[25];
  const float* fW1 = (const float*)d_in[26]; const float* fb1 = (const float*)d_in[27];

  const int* rowv = eidx;
  const int* colv = eidx + N_EDGES;

  char* ws = (char*)d_ws;
  size_t off = 0;
  auto alloc = [&](size_t bytes) -> void* {
    void* p = ws + off; off = (off + bytes + 255) & ~(size_t)255; return p;
  };
  u16*   x_b    = (u16*)alloc((size_t)N_NODES * 128 * 2);
  u16*   adjX_b = (u16*)alloc((size_t)N_NODES * 128 * 2);
  u16*   aggE_b = (u16*)alloc((size_t)N_NODES * 64 * 2);
  float* degf   = (float*)alloc((size_t)N_NODES * 4);
  int*   rowptr = (int*)alloc((size_t)(N_NODES + 1) * 4);
  int*   crow   = (int*)alloc((size_t)N_EDGES * 4);
  int*   ceid   = (int*)alloc((size_t)N_EDGES * 4);
  int*   bsum   = (int*)alloc((size_t)256 * 4);
  float* Ppart  = (float*)alloc((size_t)CGB * 8192 * 4);
  // ---- zeroed region (single memset) ----
  char*  zstart = ws + off;
  int*   cursor = (int*)alloc((size_t)N_NODES * 4);
  float* cnt    = (float*)alloc((size_t)N_NODES * 64 * 4);
  float* npool  = (float*)alloc((size_t)NB * 128 * 4);
  float* PaggE  = (float*)alloc((size_t)NB * 64 * 4);
  float* pdeg   = (float*)alloc((size_t)NB * 4);
  size_t zbytes = (size_t)((ws + off) - zstart);
  // ---- f32 weight-composition scratch ----
  float* N1a   = (float*)alloc(128 * 128 * 4);
  float* N1b   = (float*)alloc(64 * 128 * 4);
  float* N2a   = (float*)alloc(128 * 128 * 4);
  float* N2b   = (float*)alloc(128 * 128 * 4);
  float* A1    = (float*)alloc(128 * 64 * 4);
  float* B1    = (float*)alloc(128 * 64 * 4);
  float* C1    = (float*)alloc(64 * 64 * 4);
  float* G1a   = (float*)alloc(128 * 128 * 4);
  float* G1b   = (float*)alloc(64 * 128 * 4);
  float* T1    = (float*)alloc(64 * 128 * 4);
  float* U1    = (float*)alloc(128 * 128 * 4);
  float* WadjX = (float*)alloc(128 * 128 * 4);
  float* WaggE = (float*)alloc(64 * 128 * 4);
  float* Wdegx = (float*)alloc(128 * 128 * 4);
  float* c0    = (float*)alloc(64 * 4);
  float* d1    = (float*)alloc(128 * 4);
  float* d2    = (float*)alloc(128 * 4);
  float* q2    = (float*)alloc(128 * 4);
  float* ddeg  = (float*)alloc(128 * 4);
  float* e1    = (float*)alloc(128 * 4);
  float* bc    = (float*)alloc(192 * 4);
  float* bd    = (float*)alloc(192 * 4);
  u16*   BigWt = (u16*)alloc((size_t)192 * 448 * 2);
  (void)ws_size; (void)in_sizes; (void)n_in; (void)out_size;

  // ---- one memset for everything needing zeros ----
  hipMemsetAsync(zstart, 0, zbytes, stream);

  // x -> bf16 (vectorized) + deg histogram (merged)
  k_prep<<<XF8 + (N_EDGES + 255) / 256, 256, 0, stream>>>(x, x_b, colv, cursor);

  // ---- weight composition, level-batched (3 levels) ----
  {
    MMBatch L1{};
    L1.op[0]  = {n1W0, n1W1, nullptr, N1a, 128, 0,   128, 128, 128, 128};
    L1.op[1]  = {n1W0, n1W1, nullptr, N1b, 128, 128, 128, 128, 128, 64};
    L1.op[2]  = {n2W0, n2W1, nullptr, N2a, 128, 0,   128, 128, 128, 128};
    L1.op[3]  = {n2W0, n2W1, nullptr, N2b, 128, 128, 128, 128, 128, 128};
    L1.op[4]  = {eW0,  eW1,  nullptr, A1,  128, 0,   64,  128, 64,  128};
    L1.op[5]  = {eW0,  eW1,  nullptr, B1,  128, 128, 64,  128, 64,  128};
    L1.op[6]  = {eW0,  eW1,  nullptr, C1,  128, 256, 64,  128, 64,  64};
    L1.op[7]  = {g1W0, g1W1, nullptr, G1a, 128, 0,   128, 128, 128, 128};
    L1.op[8]  = {g1W0, g1W1, nullptr, G1b, 128, 128, 128, 128, 128, 64};
    L1.op[9]  = {eb0,  eW1,  eb1,     c0,  128, 0,   64,  128, 64,  1};
    L1.op[10] = {n1b0, n1W1, n1b1,    d1,  128, 0,   128, 128, 128, 1};
    L1.op[11] = {n2b0, n2W1, n2b1,    d2,  128, 0,   128, 128, 128, 1};
    L1.op[12] = {g1b0, g1W1, g1b1,    e1,  128, 0,   128, 128, 128, 1};
    k_mmb<<<dim3(128, 13), 128, 0, stream>>>(L1);

    MMBatch L2{};
    L2.op[0] = {N1b, N2b, nullptr, T1, 128, 0, 128, 128, 128, 64};
    L2.op[1] = {N1a, N2b, nullptr, U1, 128, 0, 128, 128, 128, 128};
    L2.op[2] = {c0,  N1b, d1,      q2, 64,  0, 128, 64,  128, 1};
    for (int j = 3; j < 13; ++j) L2.op[j] = {nullptr, nullptr, nullptr, nullptr, 0, 0, 0, 0, 0, 0};
    k_mmb<<<dim3(128, 3), 128, 0, stream>>>(L2);

    MMBatch L3{};
    L3.op[0] = {A1, T1, U1,      WadjX, 64,  0, 128, 64,  128, 128};
    L3.op[1] = {C1, T1, nullptr, WaggE, 64,  0, 128, 64,  128, 64};
    L3.op[2] = {B1, T1, nullptr, Wdegx, 64,  0, 128, 64,  128, 128};
    L3.op[3] = {q2, N2b, nullptr, ddeg, 128, 0, 128, 128, 128, 1};
    for (int j = 4; j < 13; ++j) L3.op[j] = {nullptr, nullptr, nullptr, nullptr, 0, 0, 0, 0, 0, 0};
    k_mmb<<<dim3(128, 4), 128, 0, stream>>>(L3);
  }
  k_pack_iter<<<337, 256, 0, stream>>>(N2a, WadjX, A1, WaggE, C1, Wdegx, B1,
                                       d2, ddeg, c0, bc, bd, BigWt);

  // ---- CSR scan + fill/cnt ----
  k_scan1<<<SCB, 256, 0, stream>>>(cursor, bsum, N_NODES);
  k_scan2<<<1, 256, 0, stream>>>(bsum, SCB);
  k_scan3<<<SCB, 256, 0, stream>>>(cursor, bsum, rowptr, cursor, degf, N_NODES);
  k_fill<<<(N_EDGES + 255) / 256, 256, 0, stream>>>(rowv, colv, batch, cursor, crow, ceid, cnt);

  const int GM = (N_NODES + 63) / 64;      // 782

  Chunks chIter;
  chIter.src[0] = x_b;    chIter.width[0] = 128; chIter.koff[0] = 0;  chIter.scl[0] = 0;
  chIter.src[1] = x_b;    chIter.width[1] = 128; chIter.koff[1] = 64; chIter.scl[1] = 0;
  chIter.src[2] = adjX_b; chIter.width[2] = 128; chIter.koff[2] = 0;  chIter.scl[2] = 0;
  chIter.src[3] = adjX_b; chIter.width[3] = 128; chIter.koff[3] = 64; chIter.scl[3] = 0;
  chIter.src[4] = aggE_b; chIter.width[4] = 64;  chIter.koff[4] = 0;  chIter.scl[4] = 0;
  chIter.src[5] = x_b;    chIter.width[5] = 128; chIter.koff[5] = 0;  chIter.scl[5] = 1;
  chIter.src[6] = x_b;    chIter.width[6] = 128; chIter.koff[6] = 64; chIter.scl[6] = 1;

  // ---- iteration 1 ----
  k_agg<true><<<2048, 256, 0, stream>>>(x_b, eattr, rowptr, crow, ceid, adjX_b, aggE_b);
  gemm_fused3<<<GM, 256, 0, stream>>>(BigWt, bc, bd, degf, chIter, N_NODES, x_b, aggE_b);
  // ---- iteration 2 ----
  k_agg<false><<<2048, 256, 0, stream>>>(x_b, nullptr, rowptr, crow, ceid, adjX_b, nullptr);
  gemm_fused3<<<GM, 256, 0, stream>>>(BigWt, bc, bd, degf, chIter, N_NODES, x_b, aggE_b);

  // ---- pooled GlobalModel path (merged cntgemm + pooling) ----
  k_cntpool<<<CGB + (N_NODES + 127) / 128, 256, 0, stream>>>(
      cnt, x_b, Ppart, aggE_b, degf, batch, npool, PaggE, pdeg, N_NODES);

  // ---- head: Ppart reduce + msg_pool + global MLP + final MLP ----
  k_head<<<NB, 256, 0, stream>>>(npool, Ppart, PaggE, pdeg, G1a, G1b, e1,
                                 g2W0, g2b0, g2W1, g2b1, fW0, fb0, fW1, fb1,
                                 (float*)d_out);
}

// Round 18
// 400.276 us; speedup vs baseline: 1.1883x; 1.0748x over previous
//
#include <hip/hip_runtime.h>
#include <hip/hip_bf16.h>

#define N_NODES 50000
#define N_EDGES 400000
#define NB 64
#define SCB 196    // ceil(N_NODES/256)
#define CGB 512
#define XF8 3125   // N_NODES*128/(256*8)

typedef unsigned short u16;
typedef unsigned int u32;
typedef __attribute__((ext_vector_type(8))) short s16x8;
typedef __attribute__((ext_vector_type(4))) float f32x4;

__device__ __forceinline__ u16 f2b(float f) {
  __hip_bfloat16 h = __float2bfloat16(f);
  return *reinterpret_cast<const u16*>(&h);
}
__device__ __forceinline__ float b2f(u16 u) {
  u32 v = ((u32)u) << 16;
  return *reinterpret_cast<const float*>(&v);
}
__device__ __forceinline__ s16x8 scl8(s16x8 v, float dg) {
  s16x8 r;
#pragma unroll
  for (int i = 0; i < 8; ++i) {
    float f = b2f((u16)v[i]) * dg;
    r[i] = (short)f2b(f);
  }
  return r;
}

// ---- merged: x f32->bf16 (vectorized, 8 elems/thread) + deg histogram ----
__global__ void k_prep(const float* __restrict__ x, u16* __restrict__ xb,
                       const int* __restrict__ colv, int* __restrict__ deg) {
  int b = blockIdx.x;
  if (b < XF8) {
    int i = (b * 256 + threadIdx.x) * 8;
    float4 v0 = *reinterpret_cast<const float4*>(&x[i]);
    float4 v1 = *reinterpret_cast<const float4*>(&x[i + 4]);
    u16 o[8] = {f2b(v0.x), f2b(v0.y), f2b(v0.z), f2b(v0.w),
                f2b(v1.x), f2b(v1.y), f2b(v1.z), f2b(v1.w)};
    *reinterpret_cast<uint4*>(&xb[i]) = *reinterpret_cast<const uint4*>(o);
  } else {
    int e = (b - XF8) * 256 + threadIdx.x;
    if (e < N_EDGES) atomicAdd(&deg[colv[e]], 1);
  }
}

// ---------------- batched small f32 matmuls ----------------
struct MMOp { const float* A; const float* B; const float* add; float* C;
              int lda, r0, ldb, K2, N, rows; };
struct MMBatch { MMOp op[13]; };

__global__ void k_mmb(MMBatch mb) {
  MMOp o = mb.op[blockIdx.y];
  int i = blockIdx.x;
  int n = threadIdx.x;
  if (i >= o.rows || n >= o.N) return;
  float acc = o.add ? o.add[(size_t)i * o.N + n] : 0.f;
  for (int k = 0; k < o.K2; ++k)
    acc = fmaf(o.A[(size_t)(o.r0 + i) * o.lda + k], o.B[(size_t)k * o.ldb + n], acc);
  o.C[(size_t)i * o.N + n] = acc;
}

// ---------------- pack composed weights (bf16, N-major) + bias pack ----------------
__global__ void k_pack_iter(const float* __restrict__ N2a, const float* __restrict__ WadjX,
                            const float* __restrict__ A1, const float* __restrict__ WaggE,
                            const float* __restrict__ C1, const float* __restrict__ Wdegx,
                            const float* __restrict__ B1,
                            const float* __restrict__ d2, const float* __restrict__ ddeg,
                            const float* __restrict__ c0,
                            float* __restrict__ bc, float* __restrict__ bd,
                            u16* __restrict__ Wt) {
  if (blockIdx.x == 336) {
    int t = threadIdx.x;
    if (t < 192) {
      bc[t] = (t < 128) ? d2[t] : 0.f;
      bd[t] = (t < 128) ? ddeg[t] : c0[t - 128];
    }
    return;
  }
  int i = blockIdx.x * 256 + threadIdx.x;
  if (i >= 192 * 448) return;
  int n = i / 448, k = i % 448;
  float v;
  if (k < 128)      v = (n < 128) ? N2a[(size_t)k * 128 + n] : 0.f;
  else if (k < 256) { int kk = k - 128; v = (n < 128) ? WadjX[(size_t)kk * 128 + n] : A1[(size_t)kk * 64 + (n - 128)]; }
  else if (k < 320) { int kk = k - 256; v = (n < 128) ? WaggE[(size_t)kk * 128 + n] : C1[(size_t)kk * 64 + (n - 128)]; }
  else              { int kk = k - 320; v = (n < 128) ? Wdegx[(size_t)kk * 128 + n] : B1[(size_t)kk * 64 + (n - 128)]; }
  Wt[(size_t)n * 448 + k] = f2b(v);
}

// ---------------- 3-phase parallel exclusive scan over deg ----------------
__global__ void k_scan1(const int* __restrict__ deg, int* __restrict__ bsum, int n) {
  __shared__ int red[256];
  int t = threadIdx.x;
  int i = blockIdx.x * 256 + t;
  red[t] = (i < n) ? deg[i] : 0;
  __syncthreads();
  for (int s = 128; s > 0; s >>= 1) {
    if (t < s) red[t] += red[t + s];
    __syncthreads();
  }
  if (t == 0) bsum[blockIdx.x] = red[0];
}

__global__ void k_scan2(int* __restrict__ bsum, int nb) {
  __shared__ int sh[256];
  int t = threadIdx.x;
  sh[t] = (t < nb) ? bsum[t] : 0;
  __syncthreads();
  for (int d = 1; d < 256; d <<= 1) {
    int v = (t >= d) ? sh[t - d] : 0;
    __syncthreads();
    sh[t] += v;
    __syncthreads();
  }
  if (t < nb) bsum[t] = sh[t];
}

__global__ void k_scan3(const int* __restrict__ deg, const int* __restrict__ bsum,
                        int* __restrict__ rowptr, int* __restrict__ cursor,
                        float* __restrict__ degf, int n) {
  __shared__ int sh[256];
  int t = threadIdx.x;
  int i = blockIdx.x * 256 + t;
  int d = (i < n) ? deg[i] : 0;
  sh[t] = d;
  __syncthreads();
  for (int s = 1; s < 256; s <<= 1) {
    int v = (t >= s) ? sh[t - s] : 0;
    __syncthreads();
    sh[t] += v;
    __syncthreads();
  }
  int base = (blockIdx.x > 0) ? bsum[blockIdx.x - 1] : 0;
  int ex = base + sh[t] - d;
  if (i < n) {
    rowptr[i] = ex;
    cursor[i] = ex;
    degf[i] = (float)d;
    if (i == n - 1) rowptr[n] = ex + d;
  }
}

// ---------------- CSR fill + cnt (thread-per-edge) ----------------
__global__ void k_fill(const int* __restrict__ rowv, const int* __restrict__ colv,
                       const int* __restrict__ batch, int* __restrict__ cursor,
                       int* __restrict__ crow, int* __restrict__ ceid,
                       float* __restrict__ cnt) {
  int i = blockIdx.x * 256 + threadIdx.x;
  if (i >= N_EDGES) return;
  int c = colv[i];
  int r = rowv[i];
  int pos = atomicAdd(&cursor[c], 1);
  crow[pos] = r;
  ceid[pos] = i;
  atomicAdd(&cnt[(size_t)r * 64 + batch[c]], 1.0f);
}

// ---------------- merged: cnt-GEMM partials (blocks < CGB) + sorted-batch pooling ----------------
__global__ __launch_bounds__(256)
void k_cntpool(const float* __restrict__ cnt, const u16* __restrict__ xb,
               float* __restrict__ Ppart,
               const u16* __restrict__ aggE, const float* __restrict__ degf,
               const int* __restrict__ batch,
               float* __restrict__ npool, float* __restrict__ PaggE,
               float* __restrict__ pdeg, int n) {
  __shared__ float cs[8][64];
  int t = threadIdx.x;
  if (blockIdx.x < CGB) {
    int c = t & 127, half = t >> 7;
    float acc[32];
#pragma unroll
    for (int q = 0; q < 32; ++q) acc[q] = 0.f;
    int span = (N_NODES + CGB - 1) / CGB;
    int v0 = blockIdx.x * span;
    int v1 = v0 + span; if (v1 > N_NODES) v1 = N_NODES;
    for (int vt = v0; vt < v1; vt += 8) {
      int nv = v1 - vt; if (nv > 8) nv = 8;
      for (int idx = t; idx < nv * 64; idx += 256)
        cs[idx >> 6][idx & 63] = cnt[(size_t)(vt + (idx >> 6)) * 64 + (idx & 63)];
      __syncthreads();
      for (int j = 0; j < nv; ++j) {
        float xv = b2f(xb[(size_t)(vt + j) * 128 + c]);
#pragma unroll
        for (int q = 0; q < 32; ++q) acc[q] = fmaf(cs[j][half * 32 + q], xv, acc[q]);
      }
      __syncthreads();
    }
#pragma unroll
    for (int q = 0; q < 32; ++q)
      Ppart[(size_t)blockIdx.x * 8192 + (size_t)(half * 32 + q) * 128 + c] = acc[q];
  } else {
    int n0 = (blockIdx.x - CGB) * 128;
    if (n0 >= n) return;
    int n1 = n0 + 128; if (n1 > n) n1 = n;
    float acc = 0.f;
    int cur = batch[n0];
    for (int i = n0; i < n1; ++i) {
      int bi = batch[i];
      if (bi != cur) {
        if (t < 128) atomicAdd(&npool[cur * 128 + t], acc);
        else if (t < 192) atomicAdd(&PaggE[cur * 64 + (t - 128)], acc);
        else if (t == 192) atomicAdd(&pdeg[cur], acc);
        acc = 0.f; cur = bi;
      }
      if (t < 128) acc += b2f(xb[(size_t)i * 128 + t]);
      else if (t < 192) acc += b2f(aggE[(size_t)i * 64 + (t - 128)]);
      else if (t == 192) acc += degf[i];
    }
    if (t < 128) atomicAdd(&npool[cur * 128 + t], acc);
    else if (t < 192) atomicAdd(&PaggE[cur * 64 + (t - 128)], acc);
    else if (t == 192) atomicAdd(&pdeg[cur], acc);
  }
}

// ---------------- CSR gather segment-sums (8/4/1 unrolled; f32 eattr via ceid) ----------------
template<bool DOE>
__global__ void k_agg(const u16* __restrict__ xb, const float* __restrict__ eaf,
                      const int* __restrict__ rowptr, const int* __restrict__ crow,
                      const int* __restrict__ ceid,
                      u16* __restrict__ outX, u16* __restrict__ outE) {
  int wpb = blockDim.x >> 6;
  int w = blockIdx.x * wpb + (threadIdx.x >> 6);
  int l = threadIdx.x & 63;
  int nw = gridDim.x * wpb;
  for (int v = w; v < N_NODES; v += nw) {
    int s = rowptr[v], e1 = rowptr[v + 1];
    float ax0 = 0.f, ax1 = 0.f, ae = 0.f;
    int i = s;
    for (; i + 7 < e1; i += 8) {
      u32 a[8]; float ev[8];
#pragma unroll
      for (int j = 0; j < 8; ++j)
        a[j] = *reinterpret_cast<const u32*>(&xb[(size_t)crow[i + j] * 128 + l * 2]);
      if (DOE) {
#pragma unroll
        for (int j = 0; j < 8; ++j)
          ev[j] = eaf[(size_t)ceid[i + j] * 64 + l];
      }
#pragma unroll
      for (int j = 0; j < 8; ++j) {
        ax0 += b2f((u16)(a[j] & 0xffff));
        ax1 += b2f((u16)(a[j] >> 16));
        if (DOE) ae += ev[j];
      }
    }
    for (; i + 3 < e1; i += 4) {
      u32 a[4]; float ev[4];
#pragma unroll
      for (int j = 0; j < 4; ++j)
        a[j] = *reinterpret_cast<const u32*>(&xb[(size_t)crow[i + j] * 128 + l * 2]);
      if (DOE) {
#pragma unroll
        for (int j = 0; j < 4; ++j)
          ev[j] = eaf[(size_t)ceid[i + j] * 64 + l];
      }
#pragma unroll
      for (int j = 0; j < 4; ++j) {
        ax0 += b2f((u16)(a[j] & 0xffff));
        ax1 += b2f((u16)(a[j] >> 16));
        if (DOE) ae += ev[j];
      }
    }
    for (; i < e1; ++i) {
      u32 a = *reinterpret_cast<const u32*>(&xb[(size_t)crow[i] * 128 + l * 2]);
      ax0 += b2f((u16)(a & 0xffff));
      ax1 += b2f((u16)(a >> 16));
      if (DOE) ae += eaf[(size_t)ceid[i] * 64 + l];
    }
    u32 pk = ((u32)f2b(ax1) << 16) | (u32)f2b(ax0);
    *reinterpret_cast<u32*>(&outX[(size_t)v * 128 + l * 2]) = pk;
    if (DOE) outE[(size_t)v * 64 + l] = f2b(ae);
  }
}

// ---------------- node GEMM v3: A direct-from-global, B LDS-staged post-barrier ----------------
struct Chunks { const u16* src[7]; int width[7]; int koff[7]; int scl[7]; };

__global__ __launch_bounds__(256)
void gemm_fused3(const u16* __restrict__ Wt,
                 const float* __restrict__ bc, const float* __restrict__ bd,
                 const float* __restrict__ degf, Chunks ch, int M,
                 u16* __restrict__ outb0, u16* __restrict__ outb1)
{
  constexpr int LDA = 72;
  __shared__ u16 Bs[192 * LDA];    // 27648 B; Cs (25600 B) aliases it
  const int t = threadIdx.x;
  const int wv = t >> 6, lane = t & 63, lr = lane & 15, lg = lane >> 4;
  const int bm0 = blockIdx.x * 64;
  const int wb = wv * 16;

  f32x4 acc[12];
#pragma unroll
  for (int f = 0; f < 12; ++f) acc[f] = (f32x4){0.f, 0.f, 0.f, 0.f};

  int arow = bm0 + wb + lr;
  if (arow >= M) arow = M - 1;
  const float dg = degf[arow];

  const int br0 = t >> 2;
  const int bo  = (t & 3) * 16;

#pragma unroll
  for (int c = 0; c < 7; ++c) {
    const u16* ap = ch.src[c] + (size_t)arow * ch.width[c] + ch.koff[c];
    s16x8 af0 = *reinterpret_cast<const s16x8*>(ap + lg * 8);
    s16x8 af1 = *reinterpret_cast<const s16x8*>(ap + 32 + lg * 8);
    if (ch.scl[c]) { af0 = scl8(af0, dg); af1 = scl8(af1, dg); }

    __syncthreads();
#pragma unroll
    for (int p = 0; p < 3; ++p) {
      const u16* bp = Wt + (size_t)(p * 64 + br0) * 448 + c * 64 + bo;
      uint4 b0 = *reinterpret_cast<const uint4*>(bp);
      uint4 b1 = *reinterpret_cast<const uint4*>(bp + 8);
      *reinterpret_cast<uint4*>(&Bs[(p * 64 + br0) * LDA + bo])     = b0;
      *reinterpret_cast<uint4*>(&Bs[(p * 64 + br0) * LDA + bo + 8]) = b1;
    }
    __syncthreads();

#pragma unroll
    for (int f = 0; f < 12; ++f) {
      s16x8 bf = *reinterpret_cast<const s16x8*>(&Bs[(f * 16 + lr) * LDA + lg * 8]);
      acc[f] = __builtin_amdgcn_mfma_f32_16x16x32_bf16(af0, bf, acc[f], 0, 0, 0);
    }
#pragma unroll
    for (int f = 0; f < 12; ++f) {
      s16x8 bf = *reinterpret_cast<const s16x8*>(&Bs[(f * 16 + lr) * LDA + 32 + lg * 8]);
      acc[f] = __builtin_amdgcn_mfma_f32_16x16x32_bf16(af1, bf, acc[f], 0, 0, 0);
    }
  }

  __syncthreads();
  u16 (*Cs)[200] = reinterpret_cast<u16(*)[200]>(Bs);
#pragma unroll
  for (int rr = 0; rr < 4; ++rr) {
    int lrow = wb + lg * 4 + rr;
    int grow = bm0 + lrow;
    float dgr = degf[(grow < M) ? grow : (M - 1)];
#pragma unroll
    for (int f = 0; f < 12; ++f) {
      int col = f * 16 + lr;
      float v = acc[f][rr] + bc[col] + dgr * bd[col];
      Cs[lrow][col] = f2b(v);
    }
  }
  __syncthreads();

#pragma unroll
  for (int p = 0; p < 4; ++p) {
    int r = p * 16 + (t >> 4), c = (t & 15) * 8;
    if (bm0 + r < M)
      *reinterpret_cast<uint4*>(&outb0[(size_t)(bm0 + r) * 128 + c]) =
          *reinterpret_cast<const uint4*>(&Cs[r][c]);
  }
#pragma unroll
  for (int p = 0; p < 2; ++p) {
    int r = p * 32 + (t >> 3), c = (t & 7) * 8;
    if (bm0 + r < M)
      *reinterpret_cast<uint4*>(&outb1[(size_t)(bm0 + r) * 64 + c]) =
          *reinterpret_cast<const uint4*>(&Cs[r][128 + c]);
  }
}

// ---------------- head: Ppart-reduce (256-thread) + msg_pool + global MLP + final MLP ----------------
__global__ void k_head(const float* __restrict__ npool, const float* __restrict__ Ppart,
                       const float* __restrict__ PaggE, const float* __restrict__ pdeg,
                       const float* __restrict__ G1a, const float* __restrict__ G1b,
                       const float* __restrict__ e1,
                       const float* __restrict__ g2W0, const float* __restrict__ g2b0,
                       const float* __restrict__ g2W1, const float* __restrict__ g2b1,
                       const float* __restrict__ fW0, const float* __restrict__ fb0,
                       const float* __restrict__ fW1, const float* __restrict__ fb1,
                       float* __restrict__ out) {
  __shared__ float padj2[256], r0[256], r1[128], r2[128], r3[256], red[256];
  float* padj = padj2;    // low 128 after combine
  int b = blockIdx.x, t = threadIdx.x;
  // Ppart reduce with all 256 threads: column t&127, j strided by 2 from t>>7
  {
    int c = t & 127, j0 = t >> 7;
    float s = 0.f;
#pragma unroll 8
    for (int j = j0; j < CGB; j += 2)
      s += Ppart[(size_t)j * 8192 + (size_t)b * 128 + c];
    padj2[t] = s;
  }
  __syncthreads();
  if (t < 128) padj[t] = padj2[t] + padj2[t + 128];
  __syncthreads();
  if (t < 128) {
    float a = pdeg[b] * e1[t];
    for (int k = 0; k < 128; ++k) a = fmaf(padj[k], G1a[(size_t)k * 128 + t], a);
    for (int k = 0; k < 64;  ++k) a = fmaf(PaggE[(size_t)b * 64 + k],  G1b[(size_t)k * 128 + t], a);
    r0[128 + t] = a;
    r0[t] = npool[(size_t)b * 128 + t];
  }
  __syncthreads();
  if (t < 128) {
    float a = g2b0[t];
    for (int k = 0; k < 256; ++k) a = fmaf(r0[k], g2W0[(size_t)k * 128 + t], a);
    r1[t] = a;
  }
  __syncthreads();
  if (t < 128) {
    float a = g2b1[t];
    for (int k = 0; k < 128; ++k) a = fmaf(r1[k], g2W1[(size_t)k * 128 + t], a);
    r2[t] = a;
  }
  __syncthreads();
  {
    float a = fb0[t];
    for (int k = 0; k < 128; ++k) a = fmaf(r2[k], fW0[(size_t)k * 256 + t], a);
    r3[t] = a;
  }
  __syncthreads();
  red[t] = r3[t] * fW1[t];
  __syncthreads();
  for (int s = 128; s > 0; s >>= 1) {
    if (t < s) red[t] += red[t + s];
    __syncthreads();
  }
  if (t == 0) out[b] = red[0] + fb1[0];
}

extern "C" void kernel_launch(void* const* d_in, const int* in_sizes, int n_in,
                              void* d_out, int out_size, void* d_ws, size_t ws_size,
                              hipStream_t stream) {
  const float* x     = (const float*)d_in[0];
  const int*   eidx  = (const int*)d_in[1];
  const float* eattr = (const float*)d_in[2];
  const int*   batch = (const int*)d_in[3];
  const float* eW0 = (const float*)d_in[4];  const float* eb0 = (const float*)d_in[5];
  const float* eW1 = (const float*)d_in[6];  const float* eb1 = (const float*)d_in[7];
  const float* n1W0 = (const float*)d_in[8]; const float* n1b0 = (const float*)d_in[9];
  const float* n1W1 = (const float*)d_in[10];const float* n1b1 = (const float*)d_in[11];
  const float* n2W0 = (const float*)d_in[12];const float* n2b0 = (const float*)d_in[13];
  const float* n2W1 = (const float*)d_in[14];const float* n2b1 = (const float*)d_in[15];
  const float* g1W0 = (const float*)d_in[16];const float* g1b0 = (const float*)d_in[17];
  const float* g1W1 = (const float*)d_in[18];const float* g1b1 = (const float*)d_in[19];
  const float* g2W0 = (const float*)d_in[20];const float* g2b0 = (const float*)d_in[21];
  const float* g2W1 = (const float*)d_in[22];const float* g2b1 = (const float*)d_in[23];
  const float* fW0 = (const float*)d_in[24]; const float* fb0 = (const float*)d_in[25];
  const float* fW1 = (const float*)d_in[26]; const float* fb1 = (const float*)d_in[27];

  const int* rowv = eidx;
  const int* colv = eidx + N_EDGES;

  char* ws = (char*)d_ws;
  size_t off = 0;
  auto alloc = [&](size_t bytes) -> void* {
    void* p = ws + off; off = (off + bytes + 255) & ~(size_t)255; return p;
  };
  u16*   x_b    = (u16*)alloc((size_t)N_NODES * 128 * 2);
  u16*   adjX_b = (u16*)alloc((size_t)N_NODES * 128 * 2);
  u16*   aggE_b = (u16*)alloc((size_t)N_NODES * 64 * 2);
  float* degf   = (float*)alloc((size_t)N_NODES * 4);
  int*   rowptr = (int*)alloc((size_t)(N_NODES + 1) * 4);
  int*   crow   = (int*)alloc((size_t)N_EDGES * 4);
  int*   ceid   = (int*)alloc((size_t)N_EDGES * 4);
  int*   bsum   = (int*)alloc((size_t)256 * 4);
  float* Ppart  = (float*)alloc((size_t)CGB * 8192 * 4);
  // ---- zeroed region (single memset) ----
  char*  zstart = ws + off;
  int*   cursor = (int*)alloc((size_t)N_NODES * 4);
  float* cnt    = (float*)alloc((size_t)N_NODES * 64 * 4);
  float* npool  = (float*)alloc((size_t)NB * 128 * 4);
  float* PaggE  = (float*)alloc((size_t)NB * 64 * 4);
  float* pdeg   = (float*)alloc((size_t)NB * 4);
  size_t zbytes = (size_t)((ws + off) - zstart);
  // ---- f32 weight-composition scratch ----
  float* N1a   = (float*)alloc(128 * 128 * 4);
  float* N1b   = (float*)alloc(64 * 128 * 4);
  float* N2a   = (float*)alloc(128 * 128 * 4);
  float* N2b   = (float*)alloc(128 * 128 * 4);
  float* A1    = (float*)alloc(128 * 64 * 4);
  float* B1    = (float*)alloc(128 * 64 * 4);
  float* C1    = (float*)alloc(64 * 64 * 4);
  float* G1a   = (float*)alloc(128 * 128 * 4);
  float* G1b   = (float*)alloc(64 * 128 * 4);
  float* T1    = (float*)alloc(64 * 128 * 4);
  float* U1    = (float*)alloc(128 * 128 * 4);
  float* WadjX = (float*)alloc(128 * 128 * 4);
  float* WaggE = (float*)alloc(64 * 128 * 4);
  float* Wdegx = (float*)alloc(128 * 128 * 4);
  float* c0    = (float*)alloc(64 * 4);
  float* d1    = (float*)alloc(128 * 4);
  float* d2    = (float*)alloc(128 * 4);
  float* q2    = (float*)alloc(128 * 4);
  float* ddeg  = (float*)alloc(128 * 4);
  float* e1    = (float*)alloc(128 * 4);
  float* bc    = (float*)alloc(192 * 4);
  float* bd    = (float*)alloc(192 * 4);
  u16*   BigWt = (u16*)alloc((size_t)192 * 448 * 2);
  (void)ws_size; (void)in_sizes; (void)n_in; (void)out_size;

  // ---- one memset for everything needing zeros ----
  hipMemsetAsync(zstart, 0, zbytes, stream);

  // x -> bf16 (vectorized) + deg histogram (merged)
  k_prep<<<XF8 + (N_EDGES + 255) / 256, 256, 0, stream>>>(x, x_b, colv, cursor);

  // ---- weight composition, level-batched (3 levels) ----
  {
    MMBatch L1{};
    L1.op[0]  = {n1W0, n1W1, nullptr, N1a, 128, 0,   128, 128, 128, 128};
    L1.op[1]  = {n1W0, n1W1, nullptr, N1b, 128, 128, 128, 128, 128, 64};
    L1.op[2]  = {n2W0, n2W1, nullptr, N2a, 128, 0,   128, 128, 128, 128};
    L1.op[3]  = {n2W0, n2W1, nullptr, N2b, 128, 128, 128, 128, 128, 128};
    L1.op[4]  = {eW0,  eW1,  nullptr, A1,  128, 0,   64,  128, 64,  128};
    L1.op[5]  = {eW0,  eW1,  nullptr, B1,  128, 128, 64,  128, 64,  128};
    L1.op[6]  = {eW0,  eW1,  nullptr, C1,  128, 256, 64,  128, 64,  64};
    L1.op[7]  = {g1W0, g1W1, nullptr, G1a, 128, 0,   128, 128, 128, 128};
    L1.op[8]  = {g1W0, g1W1, nullptr, G1b, 128, 128, 128, 128, 128, 64};
    L1.op[9]  = {eb0,  eW1,  eb1,     c0,  128, 0,   64,  128, 64,  1};
    L1.op[10] = {n1b0, n1W1, n1b1,    d1,  128, 0,   128, 128, 128, 1};
    L1.op[11] = {n2b0, n2W1, n2b1,    d2,  128, 0,   128, 128, 128, 1};
    L1.op[12] = {g1b0, g1W1, g1b1,    e1,  128, 0,   128, 128, 128, 1};
    k_mmb<<<dim3(128, 13), 128, 0, stream>>>(L1);

    MMBatch L2{};
    L2.op[0] = {N1b, N2b, nullptr, T1, 128, 0, 128, 128, 128, 64};
    L2.op[1] = {N1a, N2b, nullptr, U1, 128, 0, 128, 128, 128, 128};
    L2.op[2] = {c0,  N1b, d1,      q2, 64,  0, 128, 64,  128, 1};
    for (int j = 3; j < 13; ++j) L2.op[j] = {nullptr, nullptr, nullptr, nullptr, 0, 0, 0, 0, 0, 0};
    k_mmb<<<dim3(128, 3), 128, 0, stream>>>(L2);

    MMBatch L3{};
    L3.op[0] = {A1, T1, U1,      WadjX, 64,  0, 128, 64,  128, 128};
    L3.op[1] = {C1, T1, nullptr, WaggE, 64,  0, 128, 64,  128, 64};
    L3.op[2] = {B1, T1, nullptr, Wdegx, 64,  0, 128, 64,  128, 128};
    L3.op[3] = {q2, N2b, nullptr, ddeg, 128, 0, 128, 128, 128, 1};
    for (int j = 4; j < 13; ++j) L3.op[j] = {nullptr, nullptr, nullptr, nullptr, 0, 0, 0, 0, 0, 0};
    k_mmb<<<dim3(128, 4), 128, 0, stream>>>(L3);
  }
  k_pack_iter<<<337, 256, 0, stream>>>(N2a, WadjX, A1, WaggE, C1, Wdegx, B1,
                                       d2, ddeg, c0, bc, bd, BigWt);

  // ---- CSR scan + fill/cnt ----
  k_scan1<<<SCB, 256, 0, stream>>>(cursor, bsum, N_NODES);
  k_scan2<<<1, 256, 0, stream>>>(bsum, SCB);
  k_scan3<<<SCB, 256, 0, stream>>>(cursor, bsum, rowptr, cursor, degf, N_NODES);
  k_fill<<<(N_EDGES + 255) / 256, 256, 0, stream>>>(rowv, colv, batch, cursor, crow, ceid, cnt);

  const int GM = (N_NODES + 63) / 64;      // 782

  Chunks chIter;
  chIter.src[0] = x_b;    chIter.width[0] = 128; chIter.koff[0] = 0;  chIter.scl[0] = 0;
  chIter.src[1] = x_b;    chIter.width[1] = 128; chIter.koff[1] = 64; chIter.scl[1] = 0;
  chIter.src[2] = adjX_b; chIter.width[2] = 128; chIter.koff[2] = 0;  chIter.scl[2] = 0;
  chIter.src[3] = adjX_b; chIter.width[3] = 128; chIter.koff[3] = 64; chIter.scl[3] = 0;
  chIter.src[4] = aggE_b; chIter.width[4] = 64;  chIter.koff[4] = 0;  chIter.scl[4] = 0;
  chIter.src[5] = x_b;    chIter.width[5] = 128; chIter.koff[5] = 0;  chIter.scl[5] = 1;
  chIter.src[6] = x_b;    chIter.width[6] = 128; chIter.koff[6] = 64; chIter.scl[6] = 1;

  // ---- iteration 1 ----
  k_agg<true><<<2048, 256, 0, stream>>>(x_b, eattr, rowptr, crow, ceid, adjX_b, aggE_b);
  gemm_fused3<<<GM, 256, 0, stream>>>(BigWt, bc, bd, degf, chIter, N_NODES, x_b, aggE_b);
  // ---- iteration 2 ----
  k_agg<false><<<2048, 256, 0, stream>>>(x_b, nullptr, rowptr, crow, ceid, adjX_b, nullptr);
  gemm_fused3<<<GM, 256, 0, stream>>>(BigWt, bc, bd, degf, chIter, N_NODES, x_b, aggE_b);

  // ---- pooled GlobalModel path (merged cntgemm + pooling) ----
  k_cntpool<<<CGB + (N_NODES + 127) / 128, 256, 0, stream>>>(
      cnt, x_b, Ppart, aggE_b, degf, batch, npool, PaggE, pdeg, N_NODES);

  // ---- head: Ppart reduce + msg_pool + global MLP + final MLP ----
  k_head<<<NB, 256, 0, stream>>>(npool, Ppart, PaggE, pdeg, G1a, G1b, e1,
                                 g2W0, g2b0, g2W1, g2b1, fW0, fb0, fW1, fb1,
                                 (float*)d_out);
}